// Round 1
// baseline (880.201 us; speedup 1.0000x reference)
//
#include <hip/hip_runtime.h>
#include <hip/hip_bf16.h>

#define NTOK 197
#define BATCH 64
#define DMODEL 768
#define NHEAD 12
#define GHEAD 2
#define HRATIO 6
#define DHEAD 64
#define QKDIM 128
#define MLEV 3
#define LNEPS 1e-5f

// ---------------- NT GEMM: C = [R +] A * W^T ----------------
// A [M,K] rm, W [NC,K] rm, C [M,NC] rm. Requires M%64==0, NC%64==0, K%16==0.
template<bool RES>
__global__ __launch_bounds__(256)
void gemm_nt_kernel(const float* __restrict__ A, const float* __restrict__ W,
                    const float* __restrict__ R, float* __restrict__ C,
                    int M, int K, int NC) {
  __shared__ __align__(16) float As[16][68];
  __shared__ __align__(16) float Ws[16][68];
  const int tid = threadIdx.x;
  const int bm = blockIdx.y << 6;
  const int bn = blockIdx.x << 6;
  const int tx = tid & 15, ty = tid >> 4;
  const int lrow = tid >> 2;          // 0..63
  const int lk = (tid & 3) << 2;      // 0,4,8,12
  const float* Ap = A + (size_t)(bm + lrow) * K + lk;
  const float* Wp = W + (size_t)(bn + lrow) * K + lk;
  float acc[4][4];
#pragma unroll
  for (int i = 0; i < 4; ++i)
#pragma unroll
    for (int j = 0; j < 4; ++j) acc[i][j] = 0.f;

  for (int kt = 0; kt < K; kt += 16) {
    float4 av = *(const float4*)(Ap + kt);
    float4 wv = *(const float4*)(Wp + kt);
    __syncthreads();
    As[lk + 0][lrow] = av.x; As[lk + 1][lrow] = av.y;
    As[lk + 2][lrow] = av.z; As[lk + 3][lrow] = av.w;
    Ws[lk + 0][lrow] = wv.x; Ws[lk + 1][lrow] = wv.y;
    Ws[lk + 2][lrow] = wv.z; Ws[lk + 3][lrow] = wv.w;
    __syncthreads();
#pragma unroll
    for (int kk = 0; kk < 16; ++kk) {
      float4 a = *(const float4*)&As[kk][ty << 2];
      float4 b = *(const float4*)&Ws[kk][tx << 2];
      float ar[4] = {a.x, a.y, a.z, a.w};
      float br[4] = {b.x, b.y, b.z, b.w};
#pragma unroll
      for (int i = 0; i < 4; ++i)
#pragma unroll
        for (int j = 0; j < 4; ++j) acc[i][j] += ar[i] * br[j];
    }
  }
#pragma unroll
  for (int i = 0; i < 4; ++i) {
    size_t idx = (size_t)(bm + (ty << 2) + i) * NC + bn + (tx << 2);
    float4 o;
    o.x = acc[i][0]; o.y = acc[i][1]; o.z = acc[i][2]; o.w = acc[i][3];
    if (RES) {
      float4 r = *(const float4*)(R + idx);
      o.x += r.x; o.y += r.y; o.z += r.z; o.w += r.w;
    }
    *(float4*)(C + idx) = o;
  }
}

// ---------------- mask mix: mwT[n][i][j] = sum_l masks[i,j,l]*mproj[l,n] ---
__global__ __launch_bounds__(256)
void mw_kernel(const float* __restrict__ masks, const float* __restrict__ mproj,
               float* __restrict__ mwT) {
  int ij = blockIdx.x * 256 + threadIdx.x;
  if (ij >= NTOK * NTOK) return;
  float m0 = masks[ij * 3 + 0], m1 = masks[ij * 3 + 1], m2 = masks[ij * 3 + 2];
#pragma unroll
  for (int n = 0; n < NHEAD; ++n)
    mwT[(size_t)n * NTOK * NTOK + ij] =
        m0 * mproj[n] + m1 * mproj[NHEAD + n] + m2 * mproj[2 * NHEAD + n];
}

// ---------------- scores: score[b,g,i,j] = 0.125 * q_i . k_j --------------
__global__ __launch_bounds__(256)
void score_kernel(const float* __restrict__ q, const float* __restrict__ k,
                  float* __restrict__ score) {
  const int it = blockIdx.x;   // 0..6 (i tile of 32)
  const int b = blockIdx.y;
  const int g = blockIdx.z;
  __shared__ __align__(16) float Qs[32][68];
  __shared__ __align__(16) float Ks[32][68];
  const int tid = threadIdx.x;
  const int r = tid >> 3;             // 0..31
  const int d0 = (tid & 7) << 3;      // 0,8,...,56
  const int i0 = it << 5;
  {
    float4 v0 = {0, 0, 0, 0}, v1 = {0, 0, 0, 0};
    int i = i0 + r;
    if (i < NTOK) {
      const float* p = q + ((size_t)i * BATCH + b) * QKDIM + g * DHEAD + d0;
      v0 = *(const float4*)p;
      v1 = *(const float4*)(p + 4);
    }
    *(float4*)&Qs[r][d0] = v0;
    *(float4*)&Qs[r][d0 + 4] = v1;
  }
  const int tx = tid & 15, ty = tid >> 4;
  float* srow = score + (size_t)(b * GHEAD + g) * NTOK * NTOK;
  for (int jt = 0; jt < 7; ++jt) {
    __syncthreads();
    {
      float4 v0 = {0, 0, 0, 0}, v1 = {0, 0, 0, 0};
      int j = (jt << 5) + r;
      if (j < NTOK) {
        const float* p = k + ((size_t)j * BATCH + b) * QKDIM + g * DHEAD + d0;
        v0 = *(const float4*)p;
        v1 = *(const float4*)(p + 4);
      }
      *(float4*)&Ks[r][d0] = v0;
      *(float4*)&Ks[r][d0 + 4] = v1;
    }
    __syncthreads();
    float s00 = 0, s01 = 0, s10 = 0, s11 = 0;
#pragma unroll
    for (int d = 0; d < DHEAD; ++d) {
      float a0 = Qs[(ty << 1)][d], a1 = Qs[(ty << 1) + 1][d];
      float b0 = Ks[(tx << 1)][d], b1 = Ks[(tx << 1) + 1][d];
      s00 += a0 * b0; s01 += a0 * b1; s10 += a1 * b0; s11 += a1 * b1;
    }
    const float sc = 0.125f;
    int i = i0 + (ty << 1);
    int j = (jt << 5) + (tx << 1);
    if (i < NTOK) {
      if (j < NTOK) srow[(size_t)i * NTOK + j] = s00 * sc;
      if (j + 1 < NTOK) srow[(size_t)i * NTOK + j + 1] = s01 * sc;
    }
    if (i + 1 < NTOK) {
      if (j < NTOK) srow[(size_t)(i + 1) * NTOK + j] = s10 * sc;
      if (j + 1 < NTOK) srow[(size_t)(i + 1) * NTOK + j + 1] = s11 * sc;
    }
  }
}

// ---------------- softmax + AV per (b, head) ------------------------------
__global__ __launch_bounds__(256)
void attn_kernel(const float* __restrict__ score, const float* __restrict__ mwT,
                 const float* __restrict__ v, float* __restrict__ vec) {
  const int n = blockIdx.x;   // head
  const int b = blockIdx.y;
  const int g = n / HRATIO;
  __shared__ __align__(16) float Vs[NTOK][DHEAD];
  __shared__ float pbuf[4][200];
  const int tid = threadIdx.x;
  // stage V slice [197][64]
  for (int e = tid; e < (NTOK * DHEAD) / 4; e += 256) {
    int j = e >> 4;
    int d4 = (e & 15) << 2;
    *(float4*)&Vs[j][d4] =
        *(const float4*)(v + ((size_t)j * BATCH + b) * DMODEL + n * DHEAD + d4);
  }
  __syncthreads();
  const int w = tid >> 6, lane = tid & 63;
  const float* sbase = score + (size_t)(b * GHEAD + g) * NTOK * NTOK;
  const float* mwbase = mwT + (size_t)n * NTOK * NTOK;
  for (int i = w; i < NTOK; i += 4) {
    const float* srow = sbase + (size_t)i * NTOK;
    const float* mwrow = mwbase + (size_t)i * NTOK;
    float s[4];
    float mx = -INFINITY;
#pragma unroll
    for (int t = 0; t < 4; ++t) {
      int j = lane + (t << 6);
      if (j < NTOK) {
        s[t] = srow[j] * mwrow[j];
        mx = fmaxf(mx, s[t]);
      } else {
        s[t] = -INFINITY;
      }
    }
#pragma unroll
    for (int off = 32; off; off >>= 1) mx = fmaxf(mx, __shfl_xor(mx, off));
    float sum = 0.f;
#pragma unroll
    for (int t = 0; t < 4; ++t) {
      int j = lane + (t << 6);
      if (j < NTOK) {
        float p = __expf(s[t] - mx);
        sum += p;
        pbuf[w][j] = p;
      }
    }
#pragma unroll
    for (int off = 32; off; off >>= 1) sum += __shfl_xor(sum, off);
    float rs = 1.0f / sum;
    float acc = 0.f;
    for (int j = 0; j < NTOK; ++j) acc += pbuf[w][j] * Vs[j][lane];
    vec[((size_t)i * BATCH + b) * DMODEL + n * DHEAD + lane] = acc * rs;
  }
}

// ---------------- in-place LayerNorm over last dim (768) ------------------
__global__ __launch_bounds__(256)
void ln_kernel(float* __restrict__ x, const float* __restrict__ gamma,
               const float* __restrict__ beta) {
  const int m = blockIdx.x;
  float* row = x + (size_t)m * DMODEL;
  const int tid = threadIdx.x;
  float v0 = row[tid], v1 = row[tid + 256], v2 = row[tid + 512];
  float s = v0 + v1 + v2;
  float sq = v0 * v0 + v1 * v1 + v2 * v2;
#pragma unroll
  for (int off = 32; off; off >>= 1) {
    s += __shfl_xor(s, off);
    sq += __shfl_xor(sq, off);
  }
  __shared__ float ss[4], ssq[4];
  const int w = tid >> 6, lane = tid & 63;
  if (lane == 0) { ss[w] = s; ssq[w] = sq; }
  __syncthreads();
  s = ss[0] + ss[1] + ss[2] + ss[3];
  sq = ssq[0] + ssq[1] + ssq[2] + ssq[3];
  const float inv = 1.0f / (float)DMODEL;
  float mu = s * inv;
  float var = sq * inv - mu * mu;
  float rstd = rsqrtf(var + LNEPS);
  row[tid]       = gamma[tid]       * (v0 - mu) * rstd + beta[tid];
  row[tid + 256] = gamma[tid + 256] * (v1 - mu) * rstd + beta[tid + 256];
  row[tid + 512] = gamma[tid + 512] * (v2 - mu) * rstd + beta[tid + 512];
}

extern "C" void kernel_launch(void* const* d_in, const int* in_sizes, int n_in,
                              void* d_out, int out_size, void* d_ws, size_t ws_size,
                              hipStream_t stream) {
  const float* h     = (const float*)d_in[0];
  const float* masks = (const float*)d_in[1];
  const float* Wq    = (const float*)d_in[2];
  const float* Wk    = (const float*)d_in[3];
  const float* Wv    = (const float*)d_in[4];
  const float* Wo    = (const float*)d_in[5];
  const float* mproj = (const float*)d_in[6];
  const float* gamma = (const float*)d_in[7];
  const float* beta  = (const float*)d_in[8];
  float* out = (float*)d_out;

  float* ws = (float*)d_ws;
  size_t off = 0;
  float* q = ws + off;     off += (size_t)NTOK * BATCH * QKDIM;
  float* kbuf = ws + off;  off += (size_t)NTOK * BATCH * QKDIM;
  float* v = ws + off;     off += (size_t)NTOK * BATCH * DMODEL;
  float* score = ws + off; off += (size_t)BATCH * GHEAD * NTOK * NTOK;
  float* mwT = ws + off;   off += (size_t)NHEAD * NTOK * NTOK;
  float* vec = ws + off;   off += (size_t)NTOK * BATCH * DMODEL;

  const int M = NTOK * BATCH;  // 12608, divisible by 64

  gemm_nt_kernel<false><<<dim3(QKDIM / 64, M / 64), 256, 0, stream>>>(
      h, Wq, nullptr, q, M, DMODEL, QKDIM);
  gemm_nt_kernel<false><<<dim3(QKDIM / 64, M / 64), 256, 0, stream>>>(
      h, Wk, nullptr, kbuf, M, DMODEL, QKDIM);
  gemm_nt_kernel<false><<<dim3(DMODEL / 64, M / 64), 256, 0, stream>>>(
      h, Wv, nullptr, v, M, DMODEL, DMODEL);
  mw_kernel<<<(NTOK * NTOK + 255) / 256, 256, 0, stream>>>(masks, mproj, mwT);
  score_kernel<<<dim3(7, BATCH, GHEAD), 256, 0, stream>>>(q, kbuf, score);
  attn_kernel<<<dim3(NHEAD, BATCH), 256, 0, stream>>>(score, mwT, v, vec);
  gemm_nt_kernel<true><<<dim3(DMODEL / 64, M / 64), 256, 0, stream>>>(
      vec, Wo, h, out, M, DMODEL, DMODEL);
  ln_kernel<<<M, 256, 0, stream>>>(out, gamma, beta);
}

// Round 2
// 218.521 us; speedup vs baseline: 4.0280x; 4.0280x over previous
//
#include <hip/hip_runtime.h>
#include <hip/hip_bf16.h>
#include <stdint.h>

#define NTOK 197
#define NPAD 224
#define BATCH 64
#define DMODEL 768
#define NHEAD 12
#define GHEAD 2
#define HRATIO 6
#define DHEAD 64
#define QKDIM 128
#define LNEPS 1e-5f
#define MROWS (NTOK * BATCH)   /* 12608 */
#define MPAD 12672             /* 99 * 128 */

using f32x4 = __attribute__((ext_vector_type(4))) float;
using s16x8 = __attribute__((ext_vector_type(8))) short;
using s16x4 = __attribute__((ext_vector_type(4))) short;

__device__ __forceinline__ short f2bf(float f) {
  unsigned int x = __float_as_uint(f);
  return (short)((x + 0x7fffu + ((x >> 16) & 1u)) >> 16);
}

__device__ __forceinline__ void gld16(void* lds, const void* g) {
  __builtin_amdgcn_global_load_lds(
      (const __attribute__((address_space(1))) unsigned int*)g,
      (__attribute__((address_space(3))) unsigned int*)lds, 16, 0, 0);
}

// ---------- generic fp32 -> bf16 (count multiple of 8) ----------
__global__ __launch_bounds__(256)
void cvt_bf16_kernel(const float* __restrict__ src, short* __restrict__ dst, int n8) {
  int idx = blockIdx.x * 256 + threadIdx.x;
  if (idx >= n8) return;
  const float4* s = (const float4*)src + (size_t)idx * 2;
  float4 a = s[0], b = s[1];
  s16x8 o;
  o[0] = f2bf(a.x); o[1] = f2bf(a.y); o[2] = f2bf(a.z); o[3] = f2bf(a.w);
  o[4] = f2bf(b.x); o[5] = f2bf(b.y); o[6] = f2bf(b.z); o[7] = f2bf(b.w);
  *(s16x8*)(dst + (size_t)idx * 8) = o;
}

// ---------- concat Wq|Wk|Wv -> bf16 [1024][768] ----------
__global__ __launch_bounds__(256)
void cvt_wqkv_kernel(const float* __restrict__ Wq, const float* __restrict__ Wk,
                     const float* __restrict__ Wv, short* __restrict__ dst) {
  int r = blockIdx.x, t = threadIdx.x;
  if (t >= 192) return;
  const float* src = (r < 128) ? Wq + (size_t)r * DMODEL
                   : (r < 256) ? Wk + (size_t)(r - 128) * DMODEL
                               : Wv + (size_t)(r - 256) * DMODEL;
  float4 v = *(const float4*)(src + t * 4);
  s16x4 o; o[0] = f2bf(v.x); o[1] = f2bf(v.y); o[2] = f2bf(v.z); o[3] = f2bf(v.w);
  *(s16x4*)(dst + (size_t)r * DMODEL + t * 4) = o;
}

// ---------- bf16 NT GEMM, 128x128 tile, BK=32, MFMA 16x16x32 ----------
// OUTMODE 0: store bf16 to Cout. OUTMODE 1: store f32 + residual R.
template<int OUTMODE>
__global__ __launch_bounds__(256)
void gemm_bt_kernel(const short* __restrict__ A, const short* __restrict__ W,
                    const float* __restrict__ R, void* __restrict__ Cout,
                    int M, int K, int NC) {
  __shared__ short As[128 * 32];
  __shared__ short Ws[128 * 32];
  const int tid = threadIdx.x;
  const int bn = blockIdx.x * 128;
  const int bm = blockIdx.y * 128;
  const int w = tid >> 6, l = tid & 63;
  const int wr = w >> 1, wc = w & 1;
  const int lm = l & 15, lh = l >> 4;

  // staging: thread t -> LDS row (t>>2), slot (t&3); source chunk = slot ^ ((row>>1)&3)
  const int srow = tid >> 2;
  const int schunk = (tid & 3) ^ ((tid >> 3) & 3);
  const short* Ag = A + (size_t)(bm + srow) * K + schunk * 8;
  const short* Wg = W + (size_t)(bn + srow) * K + schunk * 8;

  const int csw = lh ^ ((lm >> 1) & 3);  // swizzled read chunk (0..3)
  f32x4 acc[4][4] = {};

  for (int kt = 0; kt < K; kt += 32) {
    __syncthreads();
    gld16(As + tid * 8, Ag + kt);
    gld16(As + 2048 + tid * 8, Ag + (size_t)64 * K + kt);
    gld16(Ws + tid * 8, Wg + kt);
    gld16(Ws + 2048 + tid * 8, Wg + (size_t)64 * K + kt);
    __syncthreads();  // compiler drains vmcnt before barrier -> LDS valid
    s16x8 af[4], bf[4];
#pragma unroll
    for (int m = 0; m < 4; ++m)
      af[m] = *(const s16x8*)((const char*)As + (wr * 64 + m * 16 + lm) * 64 + csw * 16);
#pragma unroll
    for (int n = 0; n < 4; ++n)
      bf[n] = *(const s16x8*)((const char*)Ws + (wc * 64 + n * 16 + lm) * 64 + csw * 16);
#pragma unroll
    for (int m = 0; m < 4; ++m)
#pragma unroll
      for (int n = 0; n < 4; ++n)
        acc[m][n] = __builtin_amdgcn_mfma_f32_16x16x32_bf16(af[m], bf[n], acc[m][n], 0, 0, 0);
  }

#pragma unroll
  for (int m = 0; m < 4; ++m) {
#pragma unroll
    for (int r = 0; r < 4; ++r) {
      int row = bm + wr * 64 + m * 16 + lh * 4 + r;
      if (row < M) {
        if (OUTMODE == 0) {
          short* Cb = (short*)Cout;
#pragma unroll
          for (int n = 0; n < 4; ++n) {
            int col = bn + wc * 64 + n * 16 + lm;
            Cb[(size_t)row * NC + col] = f2bf(acc[m][n][r]);
          }
        } else {
          float* Cf = (float*)Cout;
#pragma unroll
          for (int n = 0; n < 4; ++n) {
            int col = bn + wc * 64 + n * 16 + lm;
            size_t idx = (size_t)row * NC + col;
            Cf[idx] = acc[m][n][r] + R[idx];
          }
        }
      }
    }
  }
}

// ---------- pack q/k: Cb -> swizzled bf16 image [b][g][224][64] ----------
__global__ __launch_bounds__(256)
void pack_qk_kernel(const short* __restrict__ Cb, short* __restrict__ qp,
                    short* __restrict__ kp) {
  const int b = blockIdx.x, g = blockIdx.y, which = blockIdx.z;
  short* dst = (which ? kp : qp) + ((size_t)b * GHEAD + g) * NPAD * DHEAD;
  const int t = threadIdx.x;
  const int d = t & 63, iofs = t >> 6;
  for (int i0 = 0; i0 < NPAD; i0 += 4) {
    int i = i0 + iofs;
    short v = 0;
    if (i < NTOK)
      v = Cb[(size_t)(i * BATCH + b) * 1024 + which * QKDIM + g * DHEAD + d];
    dst[i * 64 + ((((d >> 3) ^ (i & 7)) << 3) | (d & 7))] = v;
  }
}

// ---------- pack v: Cb -> swizzled V^T bf16 image [b][n][64][224] ----------
__global__ __launch_bounds__(256)
void pack_v_kernel(const short* __restrict__ Cb, short* __restrict__ vT) {
  const int b = blockIdx.x, n = blockIdx.y;
  __shared__ short Vs[NPAD][DHEAD + 1];
  const int t = threadIdx.x;
  const int d = t & 63, iofs = t >> 6;
  for (int i0 = 0; i0 < NPAD; i0 += 4) {
    int i = i0 + iofs;
    short v = 0;
    if (i < NTOK)
      v = Cb[(size_t)(i * BATCH + b) * 1024 + 256 + n * DHEAD + d];
    Vs[i][d] = v;
  }
  __syncthreads();
  short* dst = vT + ((size_t)b * NHEAD + n) * DHEAD * NPAD;
  const int sub = t & 63, dr = t >> 6;
  for (int d0 = 0; d0 < DHEAD; d0 += 4) {
    if (sub < 56) {
      int dd = d0 + dr;
      int j0 = sub * 4;
      s16x4 o;
      o[0] = Vs[j0][dd]; o[1] = Vs[j0 + 1][dd];
      o[2] = Vs[j0 + 2][dd]; o[3] = Vs[j0 + 3][dd];
      int sidx = dd * NPAD + ((((j0 >> 3) ^ ((dd >> 1) & 3)) << 3) | (j0 & 4));
      *(s16x4*)(dst + sidx) = o;
    }
  }
}

// ---------- mask mix (0.125 folded in): mwT [12][197][224] ----------
__global__ __launch_bounds__(256)
void mw_kernel(const float* __restrict__ masks, const float* __restrict__ mproj,
               float* __restrict__ mwT) {
  int idx = blockIdx.x * 256 + threadIdx.x;
  if (idx >= NTOK * NPAD) return;
  int i = idx / NPAD, j = idx - i * NPAD;
  float m0 = 0.f, m1 = 0.f, m2 = 0.f;
  if (j < NTOK) {
    const float* mp = masks + (size_t)(i * NTOK + j) * 3;
    m0 = mp[0]; m1 = mp[1]; m2 = mp[2];
  }
#pragma unroll
  for (int n = 0; n < NHEAD; ++n)
    mwT[(size_t)n * NTOK * NPAD + idx] =
        0.125f * (m0 * mproj[n] + m1 * mproj[NHEAD + n] + m2 * mproj[2 * NHEAD + n]);
}

// ---------- scores via MFMA: per (b,g), C fp32 [224][224] ----------
__global__ __launch_bounds__(256)
void score_kernel(const short* __restrict__ qp, const short* __restrict__ kp,
                  float* __restrict__ score) {
  const int g = blockIdx.x, b = blockIdx.y;
  __shared__ short Qs[NPAD * 64];
  __shared__ short Ks[NPAD * 64];
  const int t = threadIdx.x;
  const short* qg = qp + ((size_t)b * GHEAD + g) * NPAD * 64;
  const short* kg = kp + ((size_t)b * GHEAD + g) * NPAD * 64;
#pragma unroll
  for (int s = 0; s < 7; ++s) {
    gld16(Qs + s * 2048 + t * 8, qg + s * 2048 + t * 8);
    gld16(Ks + s * 2048 + t * 8, kg + s * 2048 + t * 8);
  }
  __syncthreads();
  const int w = t >> 6, l = t & 63;
  const int wr = w >> 1, wc = w & 1;
  const int lm = l & 15, lh = l >> 4, l7 = l & 7;
  s16x8 aq[7][2];
#pragma unroll
  for (int mf = 0; mf < 7; ++mf)
#pragma unroll
    for (int ks = 0; ks < 2; ++ks)
      aq[mf][ks] = *(const s16x8*)((const char*)Qs +
          (wr * 112 + mf * 16 + lm) * 128 + (((ks * 4 + lh) ^ l7) << 4));
  float* sc = score + ((size_t)b * GHEAD + g) * NPAD * NPAD;
#pragma unroll
  for (int jf = 0; jf < 7; ++jf) {
    const char* kb = (const char*)Ks + (wc * 112 + jf * 16 + lm) * 128;
    s16x8 bq0 = *(const s16x8*)(kb + ((lh ^ l7) << 4));
    s16x8 bq1 = *(const s16x8*)(kb + (((4 + lh) ^ l7) << 4));
    f32x4 accj[7] = {};
#pragma unroll
    for (int mf = 0; mf < 7; ++mf) {
      accj[mf] = __builtin_amdgcn_mfma_f32_16x16x32_bf16(aq[mf][0], bq0, accj[mf], 0, 0, 0);
      accj[mf] = __builtin_amdgcn_mfma_f32_16x16x32_bf16(aq[mf][1], bq1, accj[mf], 0, 0, 0);
    }
#pragma unroll
    for (int mf = 0; mf < 7; ++mf)
#pragma unroll
      for (int r = 0; r < 4; ++r)
        sc[(size_t)(wr * 112 + mf * 16 + lh * 4 + r) * NPAD + wc * 112 + jf * 16 + lm] =
            accj[mf][r];
  }
}

// ---------- softmax + P·V via MFMA per (b, head) ----------
__global__ __launch_bounds__(256)
void attn_kernel(const float* __restrict__ score, const float* __restrict__ mwT,
                 const short* __restrict__ vT, short* __restrict__ vec_b) {
  const int n = blockIdx.x, b = blockIdx.y, g = n / HRATIO;
  __shared__ short Vt[64 * NPAD];
  __shared__ short Pt[32 * NPAD];
  __shared__ float rs[32];
  const int t = threadIdx.x;
  const short* vg = vT + ((size_t)b * NHEAD + n) * DHEAD * NPAD;
#pragma unroll
  for (int s = 0; s < 7; ++s)
    gld16(Vt + s * 2048 + t * 8, vg + s * 2048 + t * 8);
  const int w = t >> 6, l = t & 63;
  const int lm = l & 15, lh = l >> 4;
  const float* sb = score + ((size_t)b * GHEAD + g) * NPAD * NPAD;
  const float* mb = mwT + (size_t)n * NTOK * NPAD;
  __syncthreads();  // Vt staged

  for (int i0 = 0; i0 < NPAD; i0 += 32) {
    // ---- softmax: wave w owns rows (w*8 .. w*8+7) of this 32-row tile ----
    for (int rr = 0; rr < 8; ++rr) {
      const int li = w * 8 + rr;
      const int i = i0 + li;
      float tv0 = -INFINITY, tv1 = -INFINITY, tv2 = -INFINITY, tv3 = -INFINITY;
      const bool iok = (i < NTOK);
      if (iok && l < 56) {
        const float4 s4 = *(const float4*)(sb + (size_t)i * NPAD + l * 4);
        const float4 m4 = *(const float4*)(mb + (size_t)i * NPAD + l * 4);
        int j0 = l * 4;
        tv0 = (j0 + 0 < NTOK) ? s4.x * m4.x : -INFINITY;
        tv1 = (j0 + 1 < NTOK) ? s4.y * m4.y : -INFINITY;
        tv2 = (j0 + 2 < NTOK) ? s4.z * m4.z : -INFINITY;
        tv3 = (j0 + 3 < NTOK) ? s4.w * m4.w : -INFINITY;
      }
      float mx = fmaxf(fmaxf(tv0, tv1), fmaxf(tv2, tv3));
#pragma unroll
      for (int off = 32; off; off >>= 1) mx = fmaxf(mx, __shfl_xor(mx, off));
      float p0 = 0.f, p1 = 0.f, p2 = 0.f, p3 = 0.f;
      if (iok && l < 56) {
        if (tv0 > -INFINITY) p0 = __expf(tv0 - mx);
        if (tv1 > -INFINITY) p1 = __expf(tv1 - mx);
        if (tv2 > -INFINITY) p2 = __expf(tv2 - mx);
        if (tv3 > -INFINITY) p3 = __expf(tv3 - mx);
      }
      float sum = p0 + p1 + p2 + p3;
#pragma unroll
      for (int off = 32; off; off >>= 1) sum += __shfl_xor(sum, off);
      if (l == 0) rs[li] = (sum > 0.f) ? 1.f / sum : 0.f;
      if (l < 56) {
        s16x4 pv;
        pv[0] = f2bf(p0); pv[1] = f2bf(p1); pv[2] = f2bf(p2); pv[3] = f2bf(p3);
        int byteoff = li * 448 + (((l >> 1) << 4) ^ ((((li) >> 1) & 3) << 4)) + (l & 1) * 8;
        *(s16x4*)((char*)Pt + byteoff) = pv;
      }
    }
    __syncthreads();

    // ---- MFMA: wave w owns d-chunk w*16 ----
    const int cofs = (lh << 4) ^ (((lm >> 1) & 3) << 4);
    f32x4 acc0 = {}, acc1 = {};
#pragma unroll
    for (int ks = 0; ks < 7; ++ks) {
      s16x8 a0 = *(const s16x8*)((const char*)Pt + lm * 448 + ks * 64 + cofs);
      s16x8 a1 = *(const s16x8*)((const char*)Pt + (16 + lm) * 448 + ks * 64 + cofs);
      s16x8 bv = *(const s16x8*)((const char*)Vt + (w * 16 + lm) * 448 + ks * 64 + cofs);
      acc0 = __builtin_amdgcn_mfma_f32_16x16x32_bf16(a0, bv, acc0, 0, 0, 0);
      acc1 = __builtin_amdgcn_mfma_f32_16x16x32_bf16(a1, bv, acc1, 0, 0, 0);
    }
#pragma unroll
    for (int r = 0; r < 4; ++r) {
      const int li0 = lh * 4 + r;
      const int ia = i0 + li0, ib = i0 + 16 + li0;
      const int d = w * 16 + lm;
      if (ia < NTOK)
        vec_b[(size_t)(ia * BATCH + b) * DMODEL + n * DHEAD + d] = f2bf(acc0[r] * rs[li0]);
      if (ib < NTOK)
        vec_b[(size_t)(ib * BATCH + b) * DMODEL + n * DHEAD + d] = f2bf(acc1[r] * rs[li0 + 16]);
    }
    __syncthreads();
  }
}

// ---------- in-place LayerNorm over last dim (768) ----------
__global__ __launch_bounds__(256)
void ln_kernel(float* __restrict__ x, const float* __restrict__ gamma,
               const float* __restrict__ beta) {
  const int m = blockIdx.x;
  float* row = x + (size_t)m * DMODEL;
  const int tid = threadIdx.x;
  float v0 = row[tid], v1 = row[tid + 256], v2 = row[tid + 512];
  float s = v0 + v1 + v2;
  float sq = v0 * v0 + v1 * v1 + v2 * v2;
#pragma unroll
  for (int off = 32; off; off >>= 1) {
    s += __shfl_xor(s, off);
    sq += __shfl_xor(sq, off);
  }
  __shared__ float ss[4], ssq[4];
  const int w = tid >> 6, lane = tid & 63;
  if (lane == 0) { ss[w] = s; ssq[w] = sq; }
  __syncthreads();
  s = ss[0] + ss[1] + ss[2] + ss[3];
  sq = ssq[0] + ssq[1] + ssq[2] + ssq[3];
  const float inv = 1.0f / (float)DMODEL;
  float mu = s * inv;
  float var = sq * inv - mu * mu;
  float rstd = rsqrtf(var + LNEPS);
  row[tid] = gamma[tid] * (v0 - mu) * rstd + beta[tid];
  row[tid + 256] = gamma[tid + 256] * (v1 - mu) * rstd + beta[tid + 256];
  row[tid + 512] = gamma[tid + 512] * (v2 - mu) * rstd + beta[tid + 512];
}

extern "C" void kernel_launch(void* const* d_in, const int* in_sizes, int n_in,
                              void* d_out, int out_size, void* d_ws, size_t ws_size,
                              hipStream_t stream) {
  const float* h     = (const float*)d_in[0];
  const float* masks = (const float*)d_in[1];
  const float* Wq    = (const float*)d_in[2];
  const float* Wk    = (const float*)d_in[3];
  const float* Wv    = (const float*)d_in[4];
  const float* Wo    = (const float*)d_in[5];
  const float* mproj = (const float*)d_in[6];
  const float* gamma = (const float*)d_in[7];
  const float* beta  = (const float*)d_in[8];
  float* out = (float*)d_out;

  char* ws = (char*)d_ws;
  size_t o = 0;
  auto alloc = [&](size_t bytes) { size_t r = o; o += (bytes + 255) & ~(size_t)255; return r; };
  short* hb    = (short*)(ws + alloc((size_t)MPAD * DMODEL * 2));   // aliased: vec_b
  short* Cb    = (short*)(ws + alloc((size_t)MPAD * 1024 * 2));     // aliased: score
  short* Wqkvb = (short*)(ws + alloc((size_t)1024 * DMODEL * 2));
  short* Wob   = (short*)(ws + alloc((size_t)DMODEL * DMODEL * 2));
  short* qp    = (short*)(ws + alloc((size_t)BATCH * GHEAD * NPAD * DHEAD * 2));
  short* kp    = (short*)(ws + alloc((size_t)BATCH * GHEAD * NPAD * DHEAD * 2));
  short* vT    = (short*)(ws + alloc((size_t)BATCH * NHEAD * DHEAD * NPAD * 2));
  float* mwT   = (float*)(ws + alloc((size_t)NHEAD * NTOK * NPAD * 4));
  short* vec_b = hb;                 // hb dead after gemm1
  float* scoref = (float*)Cb;        // Cb dead after packs

  // 1. casts
  cvt_bf16_kernel<<<(MROWS * DMODEL / 8 + 255) / 256, 256, 0, stream>>>(h, hb, MROWS * DMODEL / 8);
  cvt_wqkv_kernel<<<1024, 256, 0, stream>>>(Wq, Wk, Wv, Wqkvb);
  cvt_bf16_kernel<<<(DMODEL * DMODEL / 8 + 255) / 256, 256, 0, stream>>>(Wo, Wob, DMODEL * DMODEL / 8);
  // 2. fused QKV projection
  gemm_bt_kernel<0><<<dim3(1024 / 128, MPAD / 128), 256, 0, stream>>>(
      hb, Wqkvb, nullptr, Cb, MROWS, DMODEL, 1024);
  // 3. packs
  pack_qk_kernel<<<dim3(BATCH, GHEAD, 2), 256, 0, stream>>>(Cb, qp, kp);
  pack_v_kernel<<<dim3(BATCH, NHEAD), 256, 0, stream>>>(Cb, vT);
  mw_kernel<<<(NTOK * NPAD + 255) / 256, 256, 0, stream>>>(masks, mproj, mwT);
  // 4. scores (overwrites Cb alias — packs complete first, same stream)
  score_kernel<<<dim3(GHEAD, BATCH), 256, 0, stream>>>(qp, kp, scoref);
  // 5. softmax + AV
  attn_kernel<<<dim3(NHEAD, BATCH), 256, 0, stream>>>(scoref, mwT, vT, vec_b);
  // 6. output projection + residual
  gemm_bt_kernel<1><<<dim3(DMODEL / 128, MPAD / 128), 256, 0, stream>>>(
      vec_b, Wob, h, out, MROWS, DMODEL, DMODEL);
  // 7. LayerNorm
  ln_kernel<<<MROWS, 256, 0, stream>>>(out, gamma, beta);
}

// Round 3
// 190.126 us; speedup vs baseline: 4.6296x; 1.1493x over previous
//
#include <hip/hip_runtime.h>
#include <hip/hip_bf16.h>
#include <stdint.h>

#define NTOK 197
#define NPAD 224
#define BATCH 64
#define DMODEL 768
#define NHEAD 12
#define GHEAD 2
#define HRATIO 6
#define DHEAD 64
#define QKDIM 128
#define LNEPS 1e-5f
#define MROWS (NTOK * BATCH)   /* 12608 */
#define MPAD 12672             /* 99 * 128 */

using f32x4 = __attribute__((ext_vector_type(4))) float;
using s16x8 = __attribute__((ext_vector_type(8))) short;
using s16x4 = __attribute__((ext_vector_type(4))) short;

__device__ __forceinline__ short f2bf(float f) {
  unsigned int x = __float_as_uint(f);
  return (short)((x + 0x7fffu + ((x >> 16) & 1u)) >> 16);
}

__device__ __forceinline__ void gld16(void* lds, const void* g) {
  __builtin_amdgcn_global_load_lds(
      (const __attribute__((address_space(1))) unsigned int*)g,
      (__attribute__((address_space(3))) unsigned int*)lds, 16, 0, 0);
}

// ---------- generic fp32 -> bf16 (count multiple of 8) ----------
__global__ __launch_bounds__(256)
void cvt_bf16_kernel(const float* __restrict__ src, short* __restrict__ dst, int n8) {
  int idx = blockIdx.x * 256 + threadIdx.x;
  if (idx >= n8) return;
  const float4* s = (const float4*)src + (size_t)idx * 2;
  float4 a = s[0], b = s[1];
  s16x8 o;
  o[0] = f2bf(a.x); o[1] = f2bf(a.y); o[2] = f2bf(a.z); o[3] = f2bf(a.w);
  o[4] = f2bf(b.x); o[5] = f2bf(b.y); o[6] = f2bf(b.z); o[7] = f2bf(b.w);
  *(s16x8*)(dst + (size_t)idx * 8) = o;
}

// ---------- concat Wq|Wk|Wv -> bf16 [1024][768] ----------
__global__ __launch_bounds__(256)
void cvt_wqkv_kernel(const float* __restrict__ Wq, const float* __restrict__ Wk,
                     const float* __restrict__ Wv, short* __restrict__ dst) {
  int r = blockIdx.x, t = threadIdx.x;
  if (t >= 192) return;
  const float* src = (r < 128) ? Wq + (size_t)r * DMODEL
                   : (r < 256) ? Wk + (size_t)(r - 128) * DMODEL
                               : Wv + (size_t)(r - 256) * DMODEL;
  float4 v = *(const float4*)(src + t * 4);
  s16x4 o; o[0] = f2bf(v.x); o[1] = f2bf(v.y); o[2] = f2bf(v.z); o[3] = f2bf(v.w);
  *(s16x4*)(dst + (size_t)r * DMODEL + t * 4) = o;
}

// ---------- bf16 NT GEMM, 128x128 tile, BK=32, MFMA 16x16x32 ----------
template<int OUTMODE>
__global__ __launch_bounds__(256)
void gemm_bt_kernel(const short* __restrict__ A, const short* __restrict__ W,
                    const float* __restrict__ R, void* __restrict__ Cout,
                    int M, int K, int NC) {
  __shared__ short As[128 * 32];
  __shared__ short Ws[128 * 32];
  const int tid = threadIdx.x;
  const int bn = blockIdx.x * 128;
  const int bm = blockIdx.y * 128;
  const int w = tid >> 6, l = tid & 63;
  const int wr = w >> 1, wc = w & 1;
  const int lm = l & 15, lh = l >> 4;

  const int srow = tid >> 2;
  const int schunk = (tid & 3) ^ ((tid >> 3) & 3);
  const short* Ag = A + (size_t)(bm + srow) * K + schunk * 8;
  const short* Wg = W + (size_t)(bn + srow) * K + schunk * 8;

  const int csw = lh ^ ((lm >> 1) & 3);
  f32x4 acc[4][4] = {};

  for (int kt = 0; kt < K; kt += 32) {
    __syncthreads();
    gld16(As + tid * 8, Ag + kt);
    gld16(As + 2048 + tid * 8, Ag + (size_t)64 * K + kt);
    gld16(Ws + tid * 8, Wg + kt);
    gld16(Ws + 2048 + tid * 8, Wg + (size_t)64 * K + kt);
    __syncthreads();
    s16x8 af[4], bf[4];
#pragma unroll
    for (int m = 0; m < 4; ++m)
      af[m] = *(const s16x8*)((const char*)As + (wr * 64 + m * 16 + lm) * 64 + csw * 16);
#pragma unroll
    for (int n = 0; n < 4; ++n)
      bf[n] = *(const s16x8*)((const char*)Ws + (wc * 64 + n * 16 + lm) * 64 + csw * 16);
#pragma unroll
    for (int m = 0; m < 4; ++m)
#pragma unroll
      for (int n = 0; n < 4; ++n)
        acc[m][n] = __builtin_amdgcn_mfma_f32_16x16x32_bf16(af[m], bf[n], acc[m][n], 0, 0, 0);
  }

#pragma unroll
  for (int m = 0; m < 4; ++m) {
#pragma unroll
    for (int r = 0; r < 4; ++r) {
      int row = bm + wr * 64 + m * 16 + lh * 4 + r;
      if (row < M) {
        if (OUTMODE == 0) {
          short* Cb = (short*)Cout;
#pragma unroll
          for (int n = 0; n < 4; ++n) {
            int col = bn + wc * 64 + n * 16 + lm;
            Cb[(size_t)row * NC + col] = f2bf(acc[m][n][r]);
          }
        } else {
          float* Cf = (float*)Cout;
#pragma unroll
          for (int n = 0; n < 4; ++n) {
            int col = bn + wc * 64 + n * 16 + lm;
            size_t idx = (size_t)row * NC + col;
            Cf[idx] = acc[m][n][r] + R[idx];
          }
        }
      }
    }
  }
}

// ---------- pack q (plain) / k (swizzled): Cb -> [b][g][224][64] ----------
__global__ __launch_bounds__(256)
void pack_qk_kernel(const short* __restrict__ Cb, short* __restrict__ qp,
                    short* __restrict__ kp) {
  const int b = blockIdx.x, g = blockIdx.y, which = blockIdx.z;
  short* dst = (which ? kp : qp) + ((size_t)b * GHEAD + g) * NPAD * DHEAD;
  const int t = threadIdx.x;
  const int d = t & 63, iofs = t >> 6;
  for (int i0 = 0; i0 < NPAD; i0 += 4) {
    int i = i0 + iofs;
    short v = 0;
    if (i < NTOK)
      v = Cb[(size_t)(i * BATCH + b) * 1024 + which * QKDIM + g * DHEAD + d];
    int dd = which ? ((((d >> 3) ^ (i & 7)) << 3) | (d & 7)) : d;
    dst[i * 64 + dd] = v;
  }
}

// ---------- pack v: Cb -> plain V^T bf16 image [b][n][64][224] ----------
__global__ __launch_bounds__(256)
void pack_v_kernel(const short* __restrict__ Cb, short* __restrict__ vT) {
  const int b = blockIdx.x, n = blockIdx.y;
  __shared__ short Vs[NPAD][DHEAD + 1];
  const int t = threadIdx.x;
  const int d = t & 63, iofs = t >> 6;
  for (int i0 = 0; i0 < NPAD; i0 += 4) {
    int i = i0 + iofs;
    short v = 0;
    if (i < NTOK)
      v = Cb[(size_t)(i * BATCH + b) * 1024 + 256 + n * DHEAD + d];
    Vs[i][d] = v;
  }
  __syncthreads();
  short* dst = vT + ((size_t)b * NHEAD + n) * DHEAD * NPAD;
  const int sub = t & 63, dr = t >> 6;
  for (int d0 = 0; d0 < DHEAD; d0 += 4) {
    if (sub < 56) {
      int dd = d0 + dr;
      int j0 = sub * 4;
      s16x4 o;
      o[0] = Vs[j0][dd]; o[1] = Vs[j0 + 1][dd];
      o[2] = Vs[j0 + 2][dd]; o[3] = Vs[j0 + 3][dd];
      *(s16x4*)(dst + dd * NPAD + j0) = o;
    }
  }
}

// ---------- mask mix (0.125 folded): mwT [12][224][224] f32, zero-padded --
__global__ __launch_bounds__(256)
void mw_kernel(const float* __restrict__ masks, const float* __restrict__ mproj,
               float* __restrict__ mwT) {
  int idx = blockIdx.x * 256 + threadIdx.x;
  if (idx >= NPAD * NPAD) return;
  int i = idx / NPAD, j = idx - i * NPAD;
  float m0 = 0.f, m1 = 0.f, m2 = 0.f;
  if (i < NTOK && j < NTOK) {
    const float* mp = masks + (size_t)(i * NTOK + j) * 3;
    m0 = mp[0]; m1 = mp[1]; m2 = mp[2];
  }
#pragma unroll
  for (int n = 0; n < NHEAD; ++n)
    mwT[(size_t)n * NPAD * NPAD + idx] =
        0.125f * (m0 * mproj[n] + m1 * mproj[NHEAD + n] + m2 * mproj[2 * NHEAD + n]);
}

// ---------- fused score + mask + softmax + PV per (b, head) ----------
// K in LDS (swizzled), Q/V fragments in registers, P in swizzled LDS.
__global__ __launch_bounds__(256, 2)
void attn_fused_kernel(const short* __restrict__ qp, const short* __restrict__ kp,
                       const short* __restrict__ vT, const float* __restrict__ mwT,
                       short* __restrict__ vec_b) {
  const int n = blockIdx.x, b = blockIdx.y, g = n / HRATIO;
  __shared__ short Ks[NPAD * 64];       // 28672 B, chunk-swizzled rows
  __shared__ short Pt[64 * 256];        // 32768 B, chunk^(row&7) swizzle
  __shared__ float rsb[64];
  const int t = threadIdx.x, w = t >> 6, l = t & 63;
  const int lm = l & 15, lh = l >> 4, l7 = l & 7;

  const short* qg = qp + ((size_t)b * GHEAD + g) * NPAD * 64;
  const short* kg = kp + ((size_t)b * GHEAD + g) * NPAD * 64;
  const short* vg = vT + ((size_t)b * NHEAD + n) * 64 * NPAD;
  const float* mb = mwT + (size_t)n * NPAD * NPAD;

  // V fragments in registers: wave w owns output dims w*16..+15
  s16x8 vf[7];
#pragma unroll
  for (int ks = 0; ks < 7; ++ks)
    vf[ks] = *(const s16x8*)(vg + (w * 16 + lm) * NPAD + ks * 32 + lh * 8);
  // Q fragments for tile 0
  s16x8 a0 = *(const s16x8*)(qg + (w * 16 + lm) * 64 + lh * 8);
  s16x8 a1 = *(const s16x8*)(qg + (w * 16 + lm) * 64 + 32 + lh * 8);
  // stage K (pre-swizzled in global -> linear LDS)
#pragma unroll
  for (int s = 0; s < 7; ++s)
    gld16(Ks + s * 2048 + t * 8, kg + s * 2048 + t * 8);
  __syncthreads();

  const int rowbase = w * 16 + lh * 4;

#pragma unroll
  for (int tt = 0; tt < 4; ++tt) {
    const int i0 = tt * 64;
    const bool rowvalid = (i0 + w * 16) < NPAD;
    if (rowvalid) {
      // ---- score: 16 rows x 224 cols per wave, in registers ----
      f32x4 acc[14] = {};
#pragma unroll
      for (int jf = 0; jf < 14; ++jf) {
        s16x8 kf0 = *(const s16x8*)((const char*)Ks + (jf * 16 + lm) * 128 + ((lh ^ l7) << 4));
        s16x8 kf1 = *(const s16x8*)((const char*)Ks + (jf * 16 + lm) * 128 + (((4 + lh) ^ l7) << 4));
        acc[jf] = __builtin_amdgcn_mfma_f32_16x16x32_bf16(a0, kf0, acc[jf], 0, 0, 0);
        acc[jf] = __builtin_amdgcn_mfma_f32_16x16x32_bf16(a1, kf1, acc[jf], 0, 0, 0);
      }
      // ---- mask-mix + softmax per row r ----
#pragma unroll
      for (int r = 0; r < 4; ++r) {
        const int row = rowbase + r;             // local row in tile
        const float* mrow = mb + (size_t)(i0 + row) * NPAD;
        float mx = -INFINITY;
#pragma unroll
        for (int jf = 0; jf < 13; ++jf) {
          float lg = acc[jf][r] * mrow[jf * 16 + lm];
          if (jf == 12 && lm >= 5) lg = -INFINITY;   // col >= 197
          acc[jf][r] = lg;
          mx = fmaxf(mx, lg);
        }
#pragma unroll
        for (int off = 8; off; off >>= 1) mx = fmaxf(mx, __shfl_xor(mx, off));
        float sum = 0.f;
#pragma unroll
        for (int jf = 0; jf < 13; ++jf) {
          float pe = __expf(acc[jf][r] - mx);
          sum += pe;
          int byteoff = row * 512 + (((2 * jf + (lm >> 3)) ^ (row & 7)) << 4) + (lm & 7) * 2;
          *(short*)((char*)Pt + byteoff) = f2bf(pe);
        }
        {  // jf = 13: all cols >= 208 invalid -> zeros
          int byteoff = row * 512 + (((26 + (lm >> 3)) ^ (row & 7)) << 4) + (lm & 7) * 2;
          *(short*)((char*)Pt + byteoff) = 0;
        }
#pragma unroll
        for (int off = 8; off; off >>= 1) sum += __shfl_xor(sum, off);
        if (lm == 0) rsb[row] = 1.f / sum;
      }
    } else {
      // zero this wave's 16 P rows (rows beyond padded range)
      s16x8 z = {};
#pragma unroll
      for (int c = 0; c < 8; ++c)
        *(s16x8*)((char*)Pt + w * 8192 + (c * 64 + l) * 16) = z;
    }
    __syncthreads();

    // prefetch next tile's Q fragments during PV
    s16x8 na0, na1;
    if (tt < 3) {
      na0 = *(const s16x8*)(qg + ((tt + 1) * 64 + w * 16 + lm) * 64 + lh * 8);
      na1 = *(const s16x8*)(qg + ((tt + 1) * 64 + w * 16 + lm) * 64 + 32 + lh * 8);
    }

    // ---- PV: wave w computes out dims w*16..+15 for all 64 rows ----
    f32x4 oacc[4] = {};
#pragma unroll
    for (int fi = 0; fi < 4; ++fi)
#pragma unroll
      for (int ks = 0; ks < 7; ++ks) {
        s16x8 pa = *(const s16x8*)((const char*)Pt + (fi * 16 + lm) * 512 +
                                   (((ks * 4 + lh) ^ l7) << 4));
        oacc[fi] = __builtin_amdgcn_mfma_f32_16x16x32_bf16(pa, vf[ks], oacc[fi], 0, 0, 0);
      }
#pragma unroll
    for (int fi = 0; fi < 4; ++fi)
#pragma unroll
      for (int r = 0; r < 4; ++r) {
        int ia = i0 + fi * 16 + lh * 4 + r;
        if (ia < NTOK) {
          float rsv = rsb[fi * 16 + lh * 4 + r];
          vec_b[((size_t)ia * BATCH + b) * DMODEL + n * 64 + w * 16 + lm] =
              f2bf(oacc[fi][r] * rsv);
        }
      }
    __syncthreads();
    a0 = na0; a1 = na1;
  }
}

// ---------- in-place LayerNorm over last dim (768) ----------
__global__ __launch_bounds__(256)
void ln_kernel(float* __restrict__ x, const float* __restrict__ gamma,
               const float* __restrict__ beta) {
  const int m = blockIdx.x;
  float* row = x + (size_t)m * DMODEL;
  const int tid = threadIdx.x;
  float v0 = row[tid], v1 = row[tid + 256], v2 = row[tid + 512];
  float s = v0 + v1 + v2;
  float sq = v0 * v0 + v1 * v1 + v2 * v2;
#pragma unroll
  for (int off = 32; off; off >>= 1) {
    s += __shfl_xor(s, off);
    sq += __shfl_xor(sq, off);
  }
  __shared__ float ss[4], ssq[4];
  const int w = tid >> 6, lane = tid & 63;
  if (lane == 0) { ss[w] = s; ssq[w] = sq; }
  __syncthreads();
  s = ss[0] + ss[1] + ss[2] + ss[3];
  sq = ssq[0] + ssq[1] + ssq[2] + ssq[3];
  const float inv = 1.0f / (float)DMODEL;
  float mu = s * inv;
  float var = sq * inv - mu * mu;
  float rstd = rsqrtf(var + LNEPS);
  row[tid] = gamma[tid] * (v0 - mu) * rstd + beta[tid];
  row[tid + 256] = gamma[tid + 256] * (v1 - mu) * rstd + beta[tid + 256];
  row[tid + 512] = gamma[tid + 512] * (v2 - mu) * rstd + beta[tid + 512];
}

extern "C" void kernel_launch(void* const* d_in, const int* in_sizes, int n_in,
                              void* d_out, int out_size, void* d_ws, size_t ws_size,
                              hipStream_t stream) {
  const float* h     = (const float*)d_in[0];
  const float* masks = (const float*)d_in[1];
  const float* Wq    = (const float*)d_in[2];
  const float* Wk    = (const float*)d_in[3];
  const float* Wv    = (const float*)d_in[4];
  const float* Wo    = (const float*)d_in[5];
  const float* mproj = (const float*)d_in[6];
  const float* gamma = (const float*)d_in[7];
  const float* beta  = (const float*)d_in[8];
  float* out = (float*)d_out;

  char* ws = (char*)d_ws;
  size_t o = 0;
  auto alloc = [&](size_t bytes) { size_t r = o; o += (bytes + 255) & ~(size_t)255; return r; };
  short* hb    = (short*)(ws + alloc((size_t)MPAD * DMODEL * 2));   // aliased: vec_b
  short* Cb    = (short*)(ws + alloc((size_t)MPAD * 1024 * 2));
  short* Wqkvb = (short*)(ws + alloc((size_t)1024 * DMODEL * 2));
  short* Wob   = (short*)(ws + alloc((size_t)DMODEL * DMODEL * 2));
  short* qp    = (short*)(ws + alloc((size_t)BATCH * GHEAD * NPAD * DHEAD * 2));
  short* kp    = (short*)(ws + alloc((size_t)BATCH * GHEAD * NPAD * DHEAD * 2));
  short* vT    = (short*)(ws + alloc((size_t)BATCH * NHEAD * DHEAD * NPAD * 2));
  float* mwT   = (float*)(ws + alloc((size_t)NHEAD * NPAD * NPAD * 4));
  short* vec_b = hb;  // hb dead after QKV gemm

  const int M = NTOK * BATCH;  // 12608

  cvt_bf16_kernel<<<(MROWS * DMODEL / 8 + 255) / 256, 256, 0, stream>>>(h, hb, MROWS * DMODEL / 8);
  cvt_wqkv_kernel<<<1024, 256, 0, stream>>>(Wq, Wk, Wv, Wqkvb);
  cvt_bf16_kernel<<<(DMODEL * DMODEL / 8 + 255) / 256, 256, 0, stream>>>(Wo, Wob, DMODEL * DMODEL / 8);
  gemm_bt_kernel<0><<<dim3(1024 / 128, MPAD / 128), 256, 0, stream>>>(
      hb, Wqkvb, nullptr, Cb, MROWS, DMODEL, 1024);
  pack_qk_kernel<<<dim3(BATCH, GHEAD, 2), 256, 0, stream>>>(Cb, qp, kp);
  pack_v_kernel<<<dim3(BATCH, NHEAD), 256, 0, stream>>>(Cb, vT);
  mw_kernel<<<(NPAD * NPAD + 255) / 256, 256, 0, stream>>>(masks, mproj, mwT);
  attn_fused_kernel<<<dim3(NHEAD, BATCH), 256, 0, stream>>>(qp, kp, vT, mwT, vec_b);
  gemm_bt_kernel<1><<<dim3(DMODEL / 128, MPAD / 128), 256, 0, stream>>>(
      vec_b, Wob, h, out, MROWS, DMODEL, DMODEL);
  ln_kernel<<<M, 256, 0, stream>>>(out, gamma, beta);
}

// Round 4
// 166.767 us; speedup vs baseline: 5.2780x; 1.1401x over previous
//
#include <hip/hip_runtime.h>
#include <hip/hip_bf16.h>
#include <stdint.h>

#define NTOK 197
#define NPAD 224
#define BATCH 64
#define DMODEL 768
#define NHEAD 12
#define GHEAD 2
#define HRATIO 6
#define DHEAD 64
#define QKDIM 128
#define LNEPS 1e-5f
#define MROWS (NTOK * BATCH)   /* 12608 */
#define MPAD 12672             /* 99 * 128 */

using f32x4 = __attribute__((ext_vector_type(4))) float;
using s16x8 = __attribute__((ext_vector_type(8))) short;
using s16x4 = __attribute__((ext_vector_type(4))) short;

__device__ __forceinline__ short f2bf(float f) {
  unsigned int x = __float_as_uint(f);
  return (short)((x + 0x7fffu + ((x >> 16) & 1u)) >> 16);
}

__device__ __forceinline__ void gld16(void* lds, const void* g) {
  __builtin_amdgcn_global_load_lds(
      (const __attribute__((address_space(1))) unsigned int*)g,
      (__attribute__((address_space(3))) unsigned int*)lds, 16, 0, 0);
}

// ---------- fused casts: h->bf16, Wq|Wk|Wv concat->bf16, Wo->bf16 ----------
#define NB_H 4728    /* (12608*768/8)/256 */
#define NB_QKV 384   /* (1024*768/8)/256 */
#define NB_WO 288    /* (768*768/8)/256 */
__global__ __launch_bounds__(256)
void prep_kernel(const float* __restrict__ h, const float* __restrict__ Wq,
                 const float* __restrict__ Wk, const float* __restrict__ Wv,
                 const float* __restrict__ Wo, short* __restrict__ hb,
                 short* __restrict__ Wqkvb, short* __restrict__ Wob) {
  const int bb = blockIdx.x, t = threadIdx.x;
  const float* src;
  short* dst;
  if (bb < NB_H) {
    int idx = bb * 256 + t;
    src = h + (size_t)idx * 8;
    dst = hb + (size_t)idx * 8;
  } else if (bb < NB_H + NB_QKV) {
    int idx = (bb - NB_H) * 256 + t;
    int r = idx / 96, u = idx - r * 96;
    const float* s0 = (r < 128) ? Wq + (size_t)r * DMODEL
                    : (r < 256) ? Wk + (size_t)(r - 128) * DMODEL
                                : Wv + (size_t)(r - 256) * DMODEL;
    src = s0 + u * 8;
    dst = Wqkvb + (size_t)r * DMODEL + u * 8;
  } else {
    int idx = (bb - NB_H - NB_QKV) * 256 + t;
    src = Wo + (size_t)idx * 8;
    dst = Wob + (size_t)idx * 8;
  }
  float4 a = *(const float4*)src;
  float4 c = *(const float4*)(src + 4);
  s16x8 o;
  o[0] = f2bf(a.x); o[1] = f2bf(a.y); o[2] = f2bf(a.z); o[3] = f2bf(a.w);
  o[4] = f2bf(c.x); o[5] = f2bf(c.y); o[6] = f2bf(c.z); o[7] = f2bf(c.w);
  *(s16x8*)dst = o;
}

// ---------- bf16 NT GEMM, 128x128 tile, BK=32, MFMA 16x16x32 ----------
template<int OUTMODE>
__global__ __launch_bounds__(256)
void gemm_bt_kernel(const short* __restrict__ A, const short* __restrict__ W,
                    const float* __restrict__ R, void* __restrict__ Cout,
                    int M, int K, int NC) {
  __shared__ short As[128 * 32];
  __shared__ short Ws[128 * 32];
  const int tid = threadIdx.x;
  const int bn = blockIdx.x * 128;
  const int bm = blockIdx.y * 128;
  const int w = tid >> 6, l = tid & 63;
  const int wr = w >> 1, wc = w & 1;
  const int lm = l & 15, lh = l >> 4;

  const int srow = tid >> 2;
  const int schunk = (tid & 3) ^ ((tid >> 3) & 3);
  const short* Ag = A + (size_t)(bm + srow) * K + schunk * 8;
  const short* Wg = W + (size_t)(bn + srow) * K + schunk * 8;

  const int csw = lh ^ ((lm >> 1) & 3);
  f32x4 acc[4][4] = {};

  for (int kt = 0; kt < K; kt += 32) {
    __syncthreads();
    gld16(As + tid * 8, Ag + kt);
    gld16(As + 2048 + tid * 8, Ag + (size_t)64 * K + kt);
    gld16(Ws + tid * 8, Wg + kt);
    gld16(Ws + 2048 + tid * 8, Wg + (size_t)64 * K + kt);
    __syncthreads();
    s16x8 af[4], bf[4];
#pragma unroll
    for (int m = 0; m < 4; ++m)
      af[m] = *(const s16x8*)((const char*)As + (wr * 64 + m * 16 + lm) * 64 + csw * 16);
#pragma unroll
    for (int n = 0; n < 4; ++n)
      bf[n] = *(const s16x8*)((const char*)Ws + (wc * 64 + n * 16 + lm) * 64 + csw * 16);
#pragma unroll
    for (int m = 0; m < 4; ++m)
#pragma unroll
      for (int n = 0; n < 4; ++n)
        acc[m][n] = __builtin_amdgcn_mfma_f32_16x16x32_bf16(af[m], bf[n], acc[m][n], 0, 0, 0);
  }

#pragma unroll
  for (int m = 0; m < 4; ++m) {
#pragma unroll
    for (int r = 0; r < 4; ++r) {
      int row = bm + wr * 64 + m * 16 + lh * 4 + r;
      if (row < M) {
        if (OUTMODE == 0) {
          short* Cb = (short*)Cout;
#pragma unroll
          for (int n = 0; n < 4; ++n) {
            int col = bn + wc * 64 + n * 16 + lm;
            Cb[(size_t)row * NC + col] = f2bf(acc[m][n][r]);
          }
        } else {
          float* Cf = (float*)Cout;
#pragma unroll
          for (int n = 0; n < 4; ++n) {
            int col = bn + wc * 64 + n * 16 + lm;
            size_t idx = (size_t)row * NC + col;
            Cf[idx] = acc[m][n][r] + R[idx];
          }
        }
      }
    }
  }
}

// ---------- fused packs: q(plain)/k(swizzled)/vT(plain) + packed mask mwp ---
// blocks [0,256): pack qk; [256,1024): pack vT; [1024,1216): mwp
__global__ __launch_bounds__(256)
void packall_kernel(const short* __restrict__ Cb, const float* __restrict__ masks,
                    const float* __restrict__ mproj, short* __restrict__ qp,
                    short* __restrict__ kp, short* __restrict__ vT,
                    float* __restrict__ mwp) {
  __shared__ short Vs[NPAD][DHEAD + 1];
  const int bb = blockIdx.x, t = threadIdx.x;
  if (bb < 256) {
    int b = bb >> 2, g = (bb >> 1) & 1, which = bb & 1;
    short* dst = (which ? kp : qp) + ((size_t)b * GHEAD + g) * NPAD * 64;
    int d = t & 63, iofs = t >> 6;
    for (int i0 = 0; i0 < NPAD; i0 += 4) {
      int i = i0 + iofs;
      short v = 0;
      if (i < NTOK)
        v = Cb[(size_t)(i * BATCH + b) * 1024 + which * QKDIM + g * DHEAD + d];
      int dd = which ? ((((d >> 3) ^ (i & 7)) << 3) | (d & 7)) : d;
      dst[i * 64 + dd] = v;
    }
  } else if (bb < 1024) {
    int vv = bb - 256;
    int b = vv / 12, n = vv - b * 12;
    int d = t & 63, iofs = t >> 6;
    for (int i0 = 0; i0 < NPAD; i0 += 4) {
      int i = i0 + iofs;
      short v = 0;
      if (i < NTOK)
        v = Cb[(size_t)(i * BATCH + b) * 1024 + 256 + n * DHEAD + d];
      Vs[i][d] = v;
    }
    __syncthreads();
    short* dst = vT + ((size_t)b * NHEAD + n) * DHEAD * NPAD;
    int sub = t & 63, dr = t >> 6;
    for (int d0 = 0; d0 < DHEAD; d0 += 4) {
      if (sub < 56) {
        int dd = d0 + dr, j0 = sub * 4;
        s16x4 o;
        o[0] = Vs[j0][dd]; o[1] = Vs[j0 + 1][dd];
        o[2] = Vs[j0 + 2][dd]; o[3] = Vs[j0 + 3][dd];
        *(s16x4*)(dst + dd * NPAD + j0) = o;
      }
    }
  } else {
    // mwp[n][i][lm][16]: lane's 14 jf values contiguous; 0.125 folded in
    int e = (bb - 1024) * 256 + t;          // < 12*256*16
    int n = e >> 12;
    int rem = e & 4095;
    int i = rem >> 4, lm = rem & 15;
    float p0 = mproj[n], p1 = mproj[NHEAD + n], p2 = mproj[2 * NHEAD + n];
    float vals[16];
#pragma unroll
    for (int jf = 0; jf < 16; ++jf) vals[jf] = 0.f;
    if (i < NTOK) {
#pragma unroll
      for (int jf = 0; jf < 14; ++jf) {
        int col = jf * 16 + lm;
        if (col < NTOK) {
          const float* mp = masks + ((size_t)i * NTOK + col) * 3;
          vals[jf] = 0.125f * (mp[0] * p0 + mp[1] * p1 + mp[2] * p2);
        }
      }
    }
    float* dst = mwp + (size_t)e * 16;
#pragma unroll
    for (int q = 0; q < 4; ++q) {
      float4 o = make_float4(vals[q * 4], vals[q * 4 + 1], vals[q * 4 + 2], vals[q * 4 + 3]);
      *(float4*)(dst + q * 4) = o;
    }
  }
}

// ---------- fused score(once) + 6x(mask+softmax+PV) per (i-tile, b, g) ------
__global__ __launch_bounds__(256, 2)
void attn_fused_kernel(const short* __restrict__ qp, const short* __restrict__ kp,
                       const short* __restrict__ vT, const float* __restrict__ mwp,
                       short* __restrict__ vec_b) {
  const int it = blockIdx.x, b = blockIdx.y, g = blockIdx.z;
  __shared__ short Ks[NPAD * 64];       // 28672 B, chunk-swizzled rows
  __shared__ short Pt[64 * 256];        // 32768 B, chunk^(row&7) swizzle
  __shared__ float rsb[64];
  const int t = threadIdx.x, w = t >> 6, l = t & 63;
  const int lm = l & 15, lh = l >> 4, l7 = l & 7;

  const short* qg = qp + ((size_t)b * GHEAD + g) * NPAD * 64;
  const short* kg = kp + ((size_t)b * GHEAD + g) * NPAD * 64;

  // stage K (pre-swizzled in global -> linear LDS)
#pragma unroll
  for (int s = 0; s < 7; ++s)
    gld16(Ks + s * 2048 + t * 8, kg + s * 2048 + t * 8);
  // Q fragments: wave w owns score rows it*64 + w*16 .. +15
  int qrow = it * 64 + w * 16 + lm;
  if (qrow > NPAD - 1) qrow = NPAD - 1;  // pad rows -> zeros; outputs discarded
  s16x8 a0 = *(const s16x8*)(qg + qrow * 64 + lh * 8);
  s16x8 a1 = *(const s16x8*)(qg + qrow * 64 + 32 + lh * 8);
  __syncthreads();

  // ---- score ONCE: 16 rows x 224 cols per wave, kept in registers ----
  f32x4 acc[14] = {};
#pragma unroll
  for (int jf = 0; jf < 14; ++jf) {
    s16x8 kf0 = *(const s16x8*)((const char*)Ks + (jf * 16 + lm) * 128 + ((lh ^ l7) << 4));
    s16x8 kf1 = *(const s16x8*)((const char*)Ks + (jf * 16 + lm) * 128 + (((4 + lh) ^ l7) << 4));
    acc[jf] = __builtin_amdgcn_mfma_f32_16x16x32_bf16(a0, kf0, acc[jf], 0, 0, 0);
    acc[jf] = __builtin_amdgcn_mfma_f32_16x16x32_bf16(a1, kf1, acc[jf], 0, 0, 0);
  }

  for (int hh = 0; hh < HRATIO; ++hh) {
    const int n = g * HRATIO + hh;
    // V fragments in registers (issued early, completes under softmax)
    const short* vg = vT + ((size_t)b * NHEAD + n) * 64 * NPAD;
    s16x8 vf[7];
#pragma unroll
    for (int ks = 0; ks < 7; ++ks)
      vf[ks] = *(const s16x8*)(vg + (w * 16 + lm) * NPAD + ks * 32 + lh * 8);

    // ---- mask-mix + no-max softmax (shift-invariant; logits bounded) ----
#pragma unroll
    for (int r = 0; r < 4; ++r) {
      const int row = w * 16 + lh * 4 + r;
      const int i = it * 64 + row;
      const float* mr = mwp + (((size_t)n * 256 + i) * 16 + lm) * 16;
      f32x4 mv0 = *(const f32x4*)(mr);
      f32x4 mv1 = *(const f32x4*)(mr + 4);
      f32x4 mv2 = *(const f32x4*)(mr + 8);
      f32x4 mv3 = *(const f32x4*)(mr + 12);
      float sum = 0.f;
#pragma unroll
      for (int jf = 0; jf < 13; ++jf) {
        float mwv = (jf < 4) ? mv0[jf] : (jf < 8) ? mv1[jf - 4]
                  : (jf < 12) ? mv2[jf - 8] : mv3[jf - 12];
        float pe = __expf(acc[jf][r] * mwv);
        if (jf == 12 && lm >= 5) pe = 0.f;   // cols >= 197
        sum += pe;
        int byteoff = row * 512 + (((2 * jf + (lm >> 3)) ^ (row & 7)) << 4) + (lm & 7) * 2;
        *(short*)((char*)Pt + byteoff) = f2bf(pe);
      }
      {  // jf = 13: cols 208-223 invalid -> zeros
        int byteoff = row * 512 + (((26 + (lm >> 3)) ^ (row & 7)) << 4) + (lm & 7) * 2;
        *(short*)((char*)Pt + byteoff) = 0;
      }
#pragma unroll
      for (int off = 8; off; off >>= 1) sum += __shfl_xor(sum, off);
      if (lm == 0) rsb[row] = 1.f / sum;
    }
    __syncthreads();

    // ---- PV: wave w computes out dims w*16..+15 for all 64 rows ----
    __builtin_amdgcn_s_setprio(1);
    f32x4 oacc[4] = {};
#pragma unroll
    for (int fi = 0; fi < 4; ++fi)
#pragma unroll
      for (int ks = 0; ks < 7; ++ks) {
        s16x8 pa = *(const s16x8*)((const char*)Pt + (fi * 16 + lm) * 512 +
                                   (((ks * 4 + lh) ^ l7) << 4));
        oacc[fi] = __builtin_amdgcn_mfma_f32_16x16x32_bf16(pa, vf[ks], oacc[fi], 0, 0, 0);
      }
    __builtin_amdgcn_s_setprio(0);
#pragma unroll
    for (int fi = 0; fi < 4; ++fi)
#pragma unroll
      for (int r = 0; r < 4; ++r) {
        int ia = it * 64 + fi * 16 + lh * 4 + r;
        if (ia < NTOK) {
          float rsv = rsb[fi * 16 + lh * 4 + r];
          vec_b[((size_t)ia * BATCH + b) * DMODEL + n * 64 + w * 16 + lm] =
              f2bf(oacc[fi][r] * rsv);
        }
      }
    __syncthreads();
  }
}

// ---------- in-place LayerNorm over last dim (768) ----------
__global__ __launch_bounds__(256)
void ln_kernel(float* __restrict__ x, const float* __restrict__ gamma,
               const float* __restrict__ beta) {
  const int m = blockIdx.x;
  float* row = x + (size_t)m * DMODEL;
  const int tid = threadIdx.x;
  float v0 = row[tid], v1 = row[tid + 256], v2 = row[tid + 512];
  float s = v0 + v1 + v2;
  float sq = v0 * v0 + v1 * v1 + v2 * v2;
#pragma unroll
  for (int off = 32; off; off >>= 1) {
    s += __shfl_xor(s, off);
    sq += __shfl_xor(sq, off);
  }
  __shared__ float ss[4], ssq[4];
  const int w = tid >> 6, lane = tid & 63;
  if (lane == 0) { ss[w] = s; ssq[w] = sq; }
  __syncthreads();
  s = ss[0] + ss[1] + ss[2] + ss[3];
  sq = ssq[0] + ssq[1] + ssq[2] + ssq[3];
  const float inv = 1.0f / (float)DMODEL;
  float mu = s * inv;
  float var = sq * inv - mu * mu;
  float rstd = rsqrtf(var + LNEPS);
  row[tid] = gamma[tid] * (v0 - mu) * rstd + beta[tid];
  row[tid + 256] = gamma[tid + 256] * (v1 - mu) * rstd + beta[tid + 256];
  row[tid + 512] = gamma[tid + 512] * (v2 - mu) * rstd + beta[tid + 512];
}

extern "C" void kernel_launch(void* const* d_in, const int* in_sizes, int n_in,
                              void* d_out, int out_size, void* d_ws, size_t ws_size,
                              hipStream_t stream) {
  const float* h     = (const float*)d_in[0];
  const float* masks = (const float*)d_in[1];
  const float* Wq    = (const float*)d_in[2];
  const float* Wk    = (const float*)d_in[3];
  const float* Wv    = (const float*)d_in[4];
  const float* Wo    = (const float*)d_in[5];
  const float* mproj = (const float*)d_in[6];
  const float* gamma = (const float*)d_in[7];
  const float* beta  = (const float*)d_in[8];
  float* out = (float*)d_out;

  char* ws = (char*)d_ws;
  size_t o = 0;
  auto alloc = [&](size_t bytes) { size_t r = o; o += (bytes + 255) & ~(size_t)255; return r; };
  short* hb    = (short*)(ws + alloc((size_t)MPAD * DMODEL * 2));   // aliased: vec_b
  short* Cb    = (short*)(ws + alloc((size_t)MPAD * 1024 * 2));
  short* Wqkvb = (short*)(ws + alloc((size_t)1024 * DMODEL * 2));
  short* Wob   = (short*)(ws + alloc((size_t)DMODEL * DMODEL * 2));
  short* qp    = (short*)(ws + alloc((size_t)BATCH * GHEAD * NPAD * DHEAD * 2));
  short* kp    = (short*)(ws + alloc((size_t)BATCH * GHEAD * NPAD * DHEAD * 2));
  short* vT    = (short*)(ws + alloc((size_t)BATCH * NHEAD * DHEAD * NPAD * 2));
  float* mwp   = (float*)(ws + alloc((size_t)NHEAD * 256 * 16 * 16 * 4));
  short* vec_b = hb;  // hb dead after QKV gemm

  prep_kernel<<<NB_H + NB_QKV + NB_WO, 256, 0, stream>>>(h, Wq, Wk, Wv, Wo, hb, Wqkvb, Wob);
  gemm_bt_kernel<0><<<dim3(1024 / 128, MPAD / 128), 256, 0, stream>>>(
      hb, Wqkvb, nullptr, Cb, MROWS, DMODEL, 1024);
  packall_kernel<<<1216, 256, 0, stream>>>(Cb, masks, mproj, qp, kp, vT, mwp);
  attn_fused_kernel<<<dim3(4, BATCH, GHEAD), 256, 0, stream>>>(qp, kp, vT, mwp, vec_b);
  gemm_bt_kernel<1><<<dim3(DMODEL / 128, MPAD / 128), 256, 0, stream>>>(
      vec_b, Wob, h, out, MROWS, DMODEL, DMODEL);
  ln_kernel<<<MROWS, 256, 0, stream>>>(out, gamma, beta);
}

// Round 5
// 155.986 us; speedup vs baseline: 5.6428x; 1.0691x over previous
//
#include <hip/hip_runtime.h>
#include <hip/hip_bf16.h>
#include <stdint.h>

#define NTOK 197
#define NPAD 224
#define BATCH 64
#define DMODEL 768
#define NHEAD 12
#define GHEAD 2
#define HRATIO 6
#define DHEAD 64
#define QKDIM 128
#define LNEPS 1e-5f
#define MROWS (NTOK * BATCH)   /* 12608 */
#define MPAD 12672             /* 99 * 128 */

using f32x4 = __attribute__((ext_vector_type(4))) float;
using s16x8 = __attribute__((ext_vector_type(8))) short;
using s16x4 = __attribute__((ext_vector_type(4))) short;

__device__ __forceinline__ short f2bf(float f) {
  unsigned int x = __float_as_uint(f);
  return (short)((x + 0x7fffu + ((x >> 16) & 1u)) >> 16);
}

__device__ __forceinline__ float bf2f(short s) {
  return __uint_as_float((unsigned)(unsigned short)s << 16);
}

__device__ __forceinline__ void gld16(void* lds, const void* g) {
  __builtin_amdgcn_global_load_lds(
      (const __attribute__((address_space(1))) unsigned int*)g,
      (__attribute__((address_space(3))) unsigned int*)lds, 16, 0, 0);
}

// ---------- fused casts: h->bf16, Wq|Wk|Wv concat->bf16, Wo->bf16 ----------
#define NB_H 4728    /* (12608*768/8)/256 */
#define NB_QKV 384   /* (1024*768/8)/256 */
#define NB_WO 288    /* (768*768/8)/256 */
__global__ __launch_bounds__(256)
void prep_kernel(const float* __restrict__ h, const float* __restrict__ Wq,
                 const float* __restrict__ Wk, const float* __restrict__ Wv,
                 const float* __restrict__ Wo, short* __restrict__ hb,
                 short* __restrict__ Wqkvb, short* __restrict__ Wob) {
  const int bb = blockIdx.x, t = threadIdx.x;
  const float* src;
  short* dst;
  if (bb < NB_H) {
    int idx = bb * 256 + t;
    src = h + (size_t)idx * 8;
    dst = hb + (size_t)idx * 8;
  } else if (bb < NB_H + NB_QKV) {
    int idx = (bb - NB_H) * 256 + t;
    int r = idx / 96, u = idx - r * 96;
    const float* s0 = (r < 128) ? Wq + (size_t)r * DMODEL
                    : (r < 256) ? Wk + (size_t)(r - 128) * DMODEL
                                : Wv + (size_t)(r - 256) * DMODEL;
    src = s0 + u * 8;
    dst = Wqkvb + (size_t)r * DMODEL + u * 8;
  } else {
    int idx = (bb - NB_H - NB_QKV) * 256 + t;
    src = Wo + (size_t)idx * 8;
    dst = Wob + (size_t)idx * 8;
  }
  float4 a = *(const float4*)src;
  float4 c = *(const float4*)(src + 4);
  s16x8 o;
  o[0] = f2bf(a.x); o[1] = f2bf(a.y); o[2] = f2bf(a.z); o[3] = f2bf(a.w);
  o[4] = f2bf(c.x); o[5] = f2bf(c.y); o[6] = f2bf(c.z); o[7] = f2bf(c.w);
  *(s16x8*)dst = o;
}

// ---------- bf16 NT GEMM, 128x128 tile, BK=32, bf16 out, XCD swizzle ------
__global__ __launch_bounds__(256)
void gemm_bt_kernel(const short* __restrict__ A, const short* __restrict__ W,
                    short* __restrict__ Cout, int M, int K, int NC) {
  __shared__ short As[128 * 32];
  __shared__ short Ws[128 * 32];
  const int tid = threadIdx.x;

  // XCD-bijective swizzle (m204): dispatch id round-robins XCDs; give each
  // XCD a contiguous chunk of logical wgids (col-fastest -> row-band stays
  // in one XCD's L2 across all its column blocks).
  const int nwg = gridDim.x * gridDim.y;
  const int orig = blockIdx.y * gridDim.x + blockIdx.x;
  const int qq = nwg >> 3, rr = nwg & 7;
  const int xcd = orig & 7, sidx = orig >> 3;
  const int wg = (xcd < rr ? xcd * (qq + 1) : rr * (qq + 1) + (xcd - rr) * qq) + sidx;
  const int bn = (wg % gridDim.x) * 128;
  const int bm = (wg / gridDim.x) * 128;

  const int w = tid >> 6, l = tid & 63;
  const int wr = w >> 1, wc = w & 1;
  const int lm = l & 15, lh = l >> 4;

  const int srow = tid >> 2;
  const int schunk = (tid & 3) ^ ((tid >> 3) & 3);
  const short* Ag = A + (size_t)(bm + srow) * K + schunk * 8;
  const short* Wg = W + (size_t)(bn + srow) * K + schunk * 8;

  const int csw = lh ^ ((lm >> 1) & 3);
  f32x4 acc[4][4] = {};

  for (int kt = 0; kt < K; kt += 32) {
    __syncthreads();
    gld16(As + tid * 8, Ag + kt);
    gld16(As + 2048 + tid * 8, Ag + (size_t)64 * K + kt);
    gld16(Ws + tid * 8, Wg + kt);
    gld16(Ws + 2048 + tid * 8, Wg + (size_t)64 * K + kt);
    __syncthreads();
    s16x8 af[4], bf[4];
#pragma unroll
    for (int m = 0; m < 4; ++m)
      af[m] = *(const s16x8*)((const char*)As + (wr * 64 + m * 16 + lm) * 64 + csw * 16);
#pragma unroll
    for (int n = 0; n < 4; ++n)
      bf[n] = *(const s16x8*)((const char*)Ws + (wc * 64 + n * 16 + lm) * 64 + csw * 16);
#pragma unroll
    for (int m = 0; m < 4; ++m)
#pragma unroll
      for (int n = 0; n < 4; ++n)
        acc[m][n] = __builtin_amdgcn_mfma_f32_16x16x32_bf16(af[m], bf[n], acc[m][n], 0, 0, 0);
  }

#pragma unroll
  for (int m = 0; m < 4; ++m) {
#pragma unroll
    for (int r = 0; r < 4; ++r) {
      int row = bm + wr * 64 + m * 16 + lh * 4 + r;
      if (row < M) {
#pragma unroll
        for (int n = 0; n < 4; ++n) {
          int col = bn + wc * 64 + n * 16 + lm;
          Cout[(size_t)row * NC + col] = f2bf(acc[m][n][r]);
        }
      }
    }
  }
}

// ---------- fused packs: q(plain)/k(swizzled)/vT(plain) + packed mask mwp ---
__global__ __launch_bounds__(256)
void packall_kernel(const short* __restrict__ Cb, const float* __restrict__ masks,
                    const float* __restrict__ mproj, short* __restrict__ qp,
                    short* __restrict__ kp, short* __restrict__ vT,
                    float* __restrict__ mwp) {
  __shared__ short Vs[NPAD][DHEAD + 1];
  const int bb = blockIdx.x, t = threadIdx.x;
  if (bb < 256) {
    int b = bb >> 2, g = (bb >> 1) & 1, which = bb & 1;
    short* dst = (which ? kp : qp) + ((size_t)b * GHEAD + g) * NPAD * 64;
    int d = t & 63, iofs = t >> 6;
    for (int i0 = 0; i0 < NPAD; i0 += 4) {
      int i = i0 + iofs;
      short v = 0;
      if (i < NTOK)
        v = Cb[(size_t)(i * BATCH + b) * 1024 + which * QKDIM + g * DHEAD + d];
      int dd = which ? ((((d >> 3) ^ (i & 7)) << 3) | (d & 7)) : d;
      dst[i * 64 + dd] = v;
    }
  } else if (bb < 1024) {
    int vv = bb - 256;
    int b = vv / 12, n = vv - b * 12;
    int d = t & 63, iofs = t >> 6;
    for (int i0 = 0; i0 < NPAD; i0 += 4) {
      int i = i0 + iofs;
      short v = 0;
      if (i < NTOK)
        v = Cb[(size_t)(i * BATCH + b) * 1024 + 256 + n * DHEAD + d];
      Vs[i][d] = v;
    }
    __syncthreads();
    short* dst = vT + ((size_t)b * NHEAD + n) * DHEAD * NPAD;
    int sub = t & 63, dr = t >> 6;
    for (int d0 = 0; d0 < DHEAD; d0 += 4) {
      if (sub < 56) {
        int dd = d0 + dr, j0 = sub * 4;
        s16x4 o;
        o[0] = Vs[j0][dd]; o[1] = Vs[j0 + 1][dd];
        o[2] = Vs[j0 + 2][dd]; o[3] = Vs[j0 + 3][dd];
        *(s16x4*)(dst + dd * NPAD + j0) = o;
      }
    }
  } else {
    // mwp[n][i][lm][16]: lane's 14 jf values contiguous; 0.125 folded in
    int e = (bb - 1024) * 256 + t;          // < 12*256*16
    int n = e >> 12;
    int rem = e & 4095;
    int i = rem >> 4, lm = rem & 15;
    float p0 = mproj[n], p1 = mproj[NHEAD + n], p2 = mproj[2 * NHEAD + n];
    float vals[16];
#pragma unroll
    for (int jf = 0; jf < 16; ++jf) vals[jf] = 0.f;
    if (i < NTOK) {
#pragma unroll
      for (int jf = 0; jf < 14; ++jf) {
        int col = jf * 16 + lm;
        if (col < NTOK) {
          const float* mp = masks + ((size_t)i * NTOK + col) * 3;
          vals[jf] = 0.125f * (mp[0] * p0 + mp[1] * p1 + mp[2] * p2);
        }
      }
    }
    float* dst = mwp + (size_t)e * 16;
#pragma unroll
    for (int q = 0; q < 4; ++q) {
      float4 o = make_float4(vals[q * 4], vals[q * 4 + 1], vals[q * 4 + 2], vals[q * 4 + 3]);
      *(float4*)(dst + q * 4) = o;
    }
  }
}

// ---------- fused score(once) + 6x(mask+softmax+PV) per (i-tile, b, g) ------
__global__ __launch_bounds__(256, 2)
void attn_fused_kernel(const short* __restrict__ qp, const short* __restrict__ kp,
                       const short* __restrict__ vT, const float* __restrict__ mwp,
                       short* __restrict__ vec_b) {
  const int it = blockIdx.x, b = blockIdx.y, g = blockIdx.z;
  __shared__ short Ks[NPAD * 64];       // 28672 B, chunk-swizzled rows
  __shared__ short Pt[64 * 256];        // 32768 B, chunk^(row&7) swizzle
  __shared__ float rsb[64];
  const int t = threadIdx.x, w = t >> 6, l = t & 63;
  const int lm = l & 15, lh = l >> 4, l7 = l & 7;

  const short* qg = qp + ((size_t)b * GHEAD + g) * NPAD * 64;
  const short* kg = kp + ((size_t)b * GHEAD + g) * NPAD * 64;

#pragma unroll
  for (int s = 0; s < 7; ++s)
    gld16(Ks + s * 2048 + t * 8, kg + s * 2048 + t * 8);
  int qrow = it * 64 + w * 16 + lm;
  if (qrow > NPAD - 1) qrow = NPAD - 1;
  s16x8 a0 = *(const s16x8*)(qg + qrow * 64 + lh * 8);
  s16x8 a1 = *(const s16x8*)(qg + qrow * 64 + 32 + lh * 8);
  __syncthreads();

  // ---- score ONCE: 16 rows x 224 cols per wave, kept in registers ----
  f32x4 acc[14] = {};
#pragma unroll
  for (int jf = 0; jf < 14; ++jf) {
    s16x8 kf0 = *(const s16x8*)((const char*)Ks + (jf * 16 + lm) * 128 + ((lh ^ l7) << 4));
    s16x8 kf1 = *(const s16x8*)((const char*)Ks + (jf * 16 + lm) * 128 + (((4 + lh) ^ l7) << 4));
    acc[jf] = __builtin_amdgcn_mfma_f32_16x16x32_bf16(a0, kf0, acc[jf], 0, 0, 0);
    acc[jf] = __builtin_amdgcn_mfma_f32_16x16x32_bf16(a1, kf1, acc[jf], 0, 0, 0);
  }

  for (int hh = 0; hh < HRATIO; ++hh) {
    const int n = g * HRATIO + hh;
    const short* vg = vT + ((size_t)b * NHEAD + n) * 64 * NPAD;
    s16x8 vf[7];
#pragma unroll
    for (int ks = 0; ks < 7; ++ks)
      vf[ks] = *(const s16x8*)(vg + (w * 16 + lm) * NPAD + ks * 32 + lh * 8);

    // ---- mask-mix + no-max softmax (shift-invariant; logits bounded) ----
#pragma unroll
    for (int r = 0; r < 4; ++r) {
      const int row = w * 16 + lh * 4 + r;
      const int i = it * 64 + row;
      const float* mr = mwp + (((size_t)n * 256 + i) * 16 + lm) * 16;
      f32x4 mv0 = *(const f32x4*)(mr);
      f32x4 mv1 = *(const f32x4*)(mr + 4);
      f32x4 mv2 = *(const f32x4*)(mr + 8);
      f32x4 mv3 = *(const f32x4*)(mr + 12);
      float sum = 0.f;
#pragma unroll
      for (int jf = 0; jf < 13; ++jf) {
        float mwv = (jf < 4) ? mv0[jf] : (jf < 8) ? mv1[jf - 4]
                  : (jf < 12) ? mv2[jf - 8] : mv3[jf - 12];
        float pe = __expf(acc[jf][r] * mwv);
        if (jf == 12 && lm >= 5) pe = 0.f;   // cols >= 197
        sum += pe;
        int byteoff = row * 512 + (((2 * jf + (lm >> 3)) ^ (row & 7)) << 4) + (lm & 7) * 2;
        *(short*)((char*)Pt + byteoff) = f2bf(pe);
      }
      {  // jf = 13: cols 208-223 invalid -> zeros
        int byteoff = row * 512 + (((26 + (lm >> 3)) ^ (row & 7)) << 4) + (lm & 7) * 2;
        *(short*)((char*)Pt + byteoff) = 0;
      }
#pragma unroll
      for (int off = 8; off; off >>= 1) sum += __shfl_xor(sum, off);
      if (lm == 0) rsb[row] = 1.f / sum;
    }
    __syncthreads();

    // ---- PV: wave w computes out dims w*16..+15 for all 64 rows ----
    __builtin_amdgcn_s_setprio(1);
    f32x4 oacc[4] = {};
#pragma unroll
    for (int fi = 0; fi < 4; ++fi)
#pragma unroll
      for (int ks = 0; ks < 7; ++ks) {
        s16x8 pa = *(const s16x8*)((const char*)Pt + (fi * 16 + lm) * 512 +
                                   (((ks * 4 + lh) ^ l7) << 4));
        oacc[fi] = __builtin_amdgcn_mfma_f32_16x16x32_bf16(pa, vf[ks], oacc[fi], 0, 0, 0);
      }
    __builtin_amdgcn_s_setprio(0);
#pragma unroll
    for (int fi = 0; fi < 4; ++fi)
#pragma unroll
      for (int r = 0; r < 4; ++r) {
        int ia = it * 64 + fi * 16 + lh * 4 + r;
        if (ia < NTOK) {
          float rsv = rsb[fi * 16 + lh * 4 + r];
          vec_b[((size_t)ia * BATCH + b) * DMODEL + n * 64 + w * 16 + lm] =
              f2bf(oacc[fi][r] * rsv);
        }
      }
    __syncthreads();
  }
}

// ---------- residual + LayerNorm: out = LN(h + proj_b) ----------
__global__ __launch_bounds__(256)
void ln_kernel(const float* __restrict__ h, const short* __restrict__ proj_b,
               float* __restrict__ out, const float* __restrict__ gamma,
               const float* __restrict__ beta) {
  const int m = blockIdx.x;
  const float* hrow = h + (size_t)m * DMODEL;
  const short* prow = proj_b + (size_t)m * DMODEL;
  float* orow = out + (size_t)m * DMODEL;
  const int tid = threadIdx.x;
  float v0 = hrow[tid] + bf2f(prow[tid]);
  float v1 = hrow[tid + 256] + bf2f(prow[tid + 256]);
  float v2 = hrow[tid + 512] + bf2f(prow[tid + 512]);
  float s = v0 + v1 + v2;
  float sq = v0 * v0 + v1 * v1 + v2 * v2;
#pragma unroll
  for (int off = 32; off; off >>= 1) {
    s += __shfl_xor(s, off);
    sq += __shfl_xor(sq, off);
  }
  __shared__ float ss[4], ssq[4];
  const int w = tid >> 6, lane = tid & 63;
  if (lane == 0) { ss[w] = s; ssq[w] = sq; }
  __syncthreads();
  s = ss[0] + ss[1] + ss[2] + ss[3];
  sq = ssq[0] + ssq[1] + ssq[2] + ssq[3];
  const float inv = 1.0f / (float)DMODEL;
  float mu = s * inv;
  float var = sq * inv - mu * mu;
  float rstd = rsqrtf(var + LNEPS);
  orow[tid] = gamma[tid] * (v0 - mu) * rstd + beta[tid];
  orow[tid + 256] = gamma[tid + 256] * (v1 - mu) * rstd + beta[tid + 256];
  orow[tid + 512] = gamma[tid + 512] * (v2 - mu) * rstd + beta[tid + 512];
}

extern "C" void kernel_launch(void* const* d_in, const int* in_sizes, int n_in,
                              void* d_out, int out_size, void* d_ws, size_t ws_size,
                              hipStream_t stream) {
  const float* h     = (const float*)d_in[0];
  const float* masks = (const float*)d_in[1];
  const float* Wq    = (const float*)d_in[2];
  const float* Wk    = (const float*)d_in[3];
  const float* Wv    = (const float*)d_in[4];
  const float* Wo    = (const float*)d_in[5];
  const float* mproj = (const float*)d_in[6];
  const float* gamma = (const float*)d_in[7];
  const float* beta  = (const float*)d_in[8];
  float* out = (float*)d_out;

  char* ws = (char*)d_ws;
  size_t o = 0;
  auto alloc = [&](size_t bytes) { size_t r = o; o += (bytes + 255) & ~(size_t)255; return r; };
  short* hb    = (short*)(ws + alloc((size_t)MPAD * DMODEL * 2));   // aliased: vec_b
  short* Cb    = (short*)(ws + alloc((size_t)MPAD * 1024 * 2));     // aliased: proj_b
  short* Wqkvb = (short*)(ws + alloc((size_t)1024 * DMODEL * 2));
  short* Wob   = (short*)(ws + alloc((size_t)DMODEL * DMODEL * 2));
  short* qp    = (short*)(ws + alloc((size_t)BATCH * GHEAD * NPAD * DHEAD * 2));
  short* kp    = (short*)(ws + alloc((size_t)BATCH * GHEAD * NPAD * DHEAD * 2));
  short* vT    = (short*)(ws + alloc((size_t)BATCH * NHEAD * DHEAD * NPAD * 2));
  float* mwp   = (float*)(ws + alloc((size_t)NHEAD * 256 * 16 * 16 * 4));
  short* vec_b = hb;   // hb dead after QKV gemm
  short* proj_b = Cb;  // Cb dead after packall

  prep_kernel<<<NB_H + NB_QKV + NB_WO, 256, 0, stream>>>(h, Wq, Wk, Wv, Wo, hb, Wqkvb, Wob);
  gemm_bt_kernel<<<dim3(1024 / 128, MPAD / 128), 256, 0, stream>>>(
      hb, Wqkvb, Cb, MROWS, DMODEL, 1024);
  packall_kernel<<<1216, 256, 0, stream>>>(Cb, masks, mproj, qp, kp, vT, mwp);
  attn_fused_kernel<<<dim3(4, BATCH, GHEAD), 256, 0, stream>>>(qp, kp, vT, mwp, vec_b);
  gemm_bt_kernel<<<dim3(DMODEL / 128, MPAD / 128), 256, 0, stream>>>(
      vec_b, Wob, proj_b, MROWS, DMODEL, DMODEL);
  ln_kernel<<<MROWS, 256, 0, stream>>>(h, proj_b, out, gamma, beta);
}

// Round 6
// 151.151 us; speedup vs baseline: 5.8233x; 1.0320x over previous
//
#include <hip/hip_runtime.h>
#include <hip/hip_bf16.h>
#include <stdint.h>

#define NTOK 197
#define NPAD 224
#define BATCH 64
#define DMODEL 768
#define NHEAD 12
#define GHEAD 2
#define HRATIO 6
#define DHEAD 64
#define QKDIM 128
#define LNEPS 1e-5f
#define MROWS (NTOK * BATCH)   /* 12608 */
#define MPAD 12672             /* 99 * 128 */

using f32x4 = __attribute__((ext_vector_type(4))) float;
using s16x8 = __attribute__((ext_vector_type(8))) short;
using s16x4 = __attribute__((ext_vector_type(4))) short;

__device__ __forceinline__ short f2bf(float f) {
  unsigned int x = __float_as_uint(f);
  return (short)((x + 0x7fffu + ((x >> 16) & 1u)) >> 16);
}

__device__ __forceinline__ float bf2f(short s) {
  return __uint_as_float((unsigned)(unsigned short)s << 16);
}

__device__ __forceinline__ void gld16(void* lds, const void* g) {
  __builtin_amdgcn_global_load_lds(
      (const __attribute__((address_space(1))) unsigned int*)g,
      (__attribute__((address_space(3))) unsigned int*)lds, 16, 0, 0);
}

// ---------- fused casts: h->bf16, Wq|Wk|Wv concat->bf16, Wo->bf16 ----------
#define NB_H 4728    /* (12608*768/8)/256 */
#define NB_QKV 384   /* (1024*768/8)/256 */
#define NB_WO 288    /* (768*768/8)/256 */
__global__ __launch_bounds__(256)
void prep_kernel(const float* __restrict__ h, const float* __restrict__ Wq,
                 const float* __restrict__ Wk, const float* __restrict__ Wv,
                 const float* __restrict__ Wo, short* __restrict__ hb,
                 short* __restrict__ Wqkvb, short* __restrict__ Wob) {
  const int bb = blockIdx.x, t = threadIdx.x;
  const float* src;
  short* dst;
  if (bb < NB_H) {
    int idx = bb * 256 + t;
    src = h + (size_t)idx * 8;
    dst = hb + (size_t)idx * 8;
  } else if (bb < NB_H + NB_QKV) {
    int idx = (bb - NB_H) * 256 + t;
    int r = idx / 96, u = idx - r * 96;
    const float* s0 = (r < 128) ? Wq + (size_t)r * DMODEL
                    : (r < 256) ? Wk + (size_t)(r - 128) * DMODEL
                                : Wv + (size_t)(r - 256) * DMODEL;
    src = s0 + u * 8;
    dst = Wqkvb + (size_t)r * DMODEL + u * 8;
  } else {
    int idx = (bb - NB_H - NB_QKV) * 256 + t;
    src = Wo + (size_t)idx * 8;
    dst = Wob + (size_t)idx * 8;
  }
  float4 a = *(const float4*)src;
  float4 c = *(const float4*)(src + 4);
  s16x8 o;
  o[0] = f2bf(a.x); o[1] = f2bf(a.y); o[2] = f2bf(a.z); o[3] = f2bf(a.w);
  o[4] = f2bf(c.x); o[5] = f2bf(c.y); o[6] = f2bf(c.z); o[7] = f2bf(c.w);
  *(s16x8*)dst = o;
}

// ---------- bf16 NT GEMM, 128x128 tile, BK=32, dbuf-pipelined, XCD swz -----
__global__ __launch_bounds__(256)
void gemm_bt_kernel(const short* __restrict__ A, const short* __restrict__ W,
                    short* __restrict__ Cout, int M, int K, int NC) {
  __shared__ short As[2 * 128 * 32];
  __shared__ short Ws[2 * 128 * 32];
  const int tid = threadIdx.x;

  // XCD-bijective swizzle (m204): give each XCD a contiguous chunk of
  // logical wgids (col-fastest -> row-band stays in one XCD's L2).
  const int nwg = gridDim.x * gridDim.y;
  const int orig = blockIdx.y * gridDim.x + blockIdx.x;
  const int qq = nwg >> 3, rr = nwg & 7;
  const int xcd = orig & 7, sidx = orig >> 3;
  const int wg = (xcd < rr ? xcd * (qq + 1) : rr * (qq + 1) + (xcd - rr) * qq) + sidx;
  const int bn = (wg % gridDim.x) * 128;
  const int bm = (wg / gridDim.x) * 128;

  const int w = tid >> 6, l = tid & 63;
  const int wr = w >> 1, wc = w & 1;
  const int lm = l & 15, lh = l >> 4;

  const int srow = tid >> 2;
  const int schunk = (tid & 3) ^ ((tid >> 3) & 3);
  const short* Ag = A + (size_t)(bm + srow) * K + schunk * 8;
  const short* Wg = W + (size_t)(bn + srow) * K + schunk * 8;

  const int csw = lh ^ ((lm >> 1) & 3);
  f32x4 acc[4][4] = {};

#define STAGE(buf, kt)                                              \
  do {                                                              \
    gld16(As + (buf) * 4096 + tid * 8, Ag + (kt));                  \
    gld16(As + (buf) * 4096 + 2048 + tid * 8, Ag + (size_t)64 * K + (kt)); \
    gld16(Ws + (buf) * 4096 + tid * 8, Wg + (kt));                  \
    gld16(Ws + (buf) * 4096 + 2048 + tid * 8, Wg + (size_t)64 * K + (kt)); \
  } while (0)

  const int NK = K >> 5;  // 24
  STAGE(0, 0);
  for (int ki = 0; ki < NK; ++ki) {
    const int cur = ki & 1;
    // current buffer's loads were issued one full compute phase ago
    asm volatile("s_waitcnt vmcnt(0)" ::: "memory");
    __builtin_amdgcn_s_barrier();
    if (ki + 1 < NK) STAGE(cur ^ 1, (ki + 1) * 32);   // stays in flight
    const char* Ab = (const char*)(As + cur * 4096);
    const char* Bb = (const char*)(Ws + cur * 4096);
    s16x8 af[4], bf[4];
#pragma unroll
    for (int m = 0; m < 4; ++m)
      af[m] = *(const s16x8*)(Ab + (wr * 64 + m * 16 + lm) * 64 + csw * 16);
#pragma unroll
    for (int n = 0; n < 4; ++n)
      bf[n] = *(const s16x8*)(Bb + (wc * 64 + n * 16 + lm) * 64 + csw * 16);
#pragma unroll
    for (int m = 0; m < 4; ++m)
#pragma unroll
      for (int n = 0; n < 4; ++n)
        acc[m][n] = __builtin_amdgcn_mfma_f32_16x16x32_bf16(af[m], bf[n], acc[m][n], 0, 0, 0);
    // all waves must finish reading cur before iter ki+1 overwrites it
    asm volatile("s_waitcnt lgkmcnt(0)" ::: "memory");
    __builtin_amdgcn_s_barrier();
  }
#undef STAGE

#pragma unroll
  for (int m = 0; m < 4; ++m) {
#pragma unroll
    for (int r = 0; r < 4; ++r) {
      int row = bm + wr * 64 + m * 16 + lh * 4 + r;
      if (row < M) {
#pragma unroll
        for (int n = 0; n < 4; ++n) {
          int col = bn + wc * 64 + n * 16 + lm;
          Cout[(size_t)row * NC + col] = f2bf(acc[m][n][r]);
        }
      }
    }
  }
}

// ---------- fused packs: q(plain)/k(swizzled)/vT(plain) + packed mask mwp ---
__global__ __launch_bounds__(256)
void packall_kernel(const short* __restrict__ Cb, const float* __restrict__ masks,
                    const float* __restrict__ mproj, short* __restrict__ qp,
                    short* __restrict__ kp, short* __restrict__ vT,
                    float* __restrict__ mwp) {
  __shared__ short Vs[NPAD][DHEAD + 1];
  const int bb = blockIdx.x, t = threadIdx.x;
  if (bb < 256) {
    int b = bb >> 2, g = (bb >> 1) & 1, which = bb & 1;
    short* dst = (which ? kp : qp) + ((size_t)b * GHEAD + g) * NPAD * 64;
    int d = t & 63, iofs = t >> 6;
    for (int i0 = 0; i0 < NPAD; i0 += 4) {
      int i = i0 + iofs;
      short v = 0;
      if (i < NTOK)
        v = Cb[(size_t)(i * BATCH + b) * 1024 + which * QKDIM + g * DHEAD + d];
      int dd = which ? ((((d >> 3) ^ (i & 7)) << 3) | (d & 7)) : d;
      dst[i * 64 + dd] = v;
    }
  } else if (bb < 1024) {
    int vv = bb - 256;
    int b = vv / 12, n = vv - b * 12;
    int d = t & 63, iofs = t >> 6;
    for (int i0 = 0; i0 < NPAD; i0 += 4) {
      int i = i0 + iofs;
      short v = 0;
      if (i < NTOK)
        v = Cb[(size_t)(i * BATCH + b) * 1024 + 256 + n * DHEAD + d];
      Vs[i][d] = v;
    }
    __syncthreads();
    short* dst = vT + ((size_t)b * NHEAD + n) * DHEAD * NPAD;
    int sub = t & 63, dr = t >> 6;
    for (int d0 = 0; d0 < DHEAD; d0 += 4) {
      if (sub < 56) {
        int dd = d0 + dr, j0 = sub * 4;
        s16x4 o;
        o[0] = Vs[j0][dd]; o[1] = Vs[j0 + 1][dd];
        o[2] = Vs[j0 + 2][dd]; o[3] = Vs[j0 + 3][dd];
        *(s16x4*)(dst + dd * NPAD + j0) = o;
      }
    }
  } else {
    // mwp[n][i][lm][16]: lane's 14 jf values contiguous; 0.125 folded in
    int e = (bb - 1024) * 256 + t;          // < 12*256*16
    int n = e >> 12;
    int rem = e & 4095;
    int i = rem >> 4, lm = rem & 15;
    float p0 = mproj[n], p1 = mproj[NHEAD + n], p2 = mproj[2 * NHEAD + n];
    float vals[16];
#pragma unroll
    for (int jf = 0; jf < 16; ++jf) vals[jf] = 0.f;
    if (i < NTOK) {
#pragma unroll
      for (int jf = 0; jf < 14; ++jf) {
        int col = jf * 16 + lm;
        if (col < NTOK) {
          const float* mp = masks + ((size_t)i * NTOK + col) * 3;
          vals[jf] = 0.125f * (mp[0] * p0 + mp[1] * p1 + mp[2] * p2);
        }
      }
    }
    float* dst = mwp + (size_t)e * 16;
#pragma unroll
    for (int q = 0; q < 4; ++q) {
      float4 o = make_float4(vals[q * 4], vals[q * 4 + 1], vals[q * 4 + 2], vals[q * 4 + 3]);
      *(float4*)(dst + q * 4) = o;
    }
  }
}

// ---------- fused score(once) + 6x(mask+softmax+PV) per (i-tile, b, g) ------
__global__ __launch_bounds__(256, 2)
void attn_fused_kernel(const short* __restrict__ qp, const short* __restrict__ kp,
                       const short* __restrict__ vT, const float* __restrict__ mwp,
                       short* __restrict__ vec_b) {
  const int it = blockIdx.x, b = blockIdx.y, g = blockIdx.z;
  __shared__ short Ks[NPAD * 64];       // 28672 B, chunk-swizzled rows
  __shared__ short Pt[64 * 256];        // 32768 B, chunk^(row&7) swizzle
  __shared__ float rsb[64];
  const int t = threadIdx.x, w = t >> 6, l = t & 63;
  const int lm = l & 15, lh = l >> 4, l7 = l & 7;

  const short* qg = qp + ((size_t)b * GHEAD + g) * NPAD * 64;
  const short* kg = kp + ((size_t)b * GHEAD + g) * NPAD * 64;

#pragma unroll
  for (int s = 0; s < 7; ++s)
    gld16(Ks + s * 2048 + t * 8, kg + s * 2048 + t * 8);
  int qrow = it * 64 + w * 16 + lm;
  if (qrow > NPAD - 1) qrow = NPAD - 1;
  s16x8 a0 = *(const s16x8*)(qg + qrow * 64 + lh * 8);
  s16x8 a1 = *(const s16x8*)(qg + qrow * 64 + 32 + lh * 8);
  __syncthreads();

  // ---- score ONCE: 16 rows x 224 cols per wave, kept in registers ----
  f32x4 acc[14] = {};
#pragma unroll
  for (int jf = 0; jf < 14; ++jf) {
    s16x8 kf0 = *(const s16x8*)((const char*)Ks + (jf * 16 + lm) * 128 + ((lh ^ l7) << 4));
    s16x8 kf1 = *(const s16x8*)((const char*)Ks + (jf * 16 + lm) * 128 + (((4 + lh) ^ l7) << 4));
    acc[jf] = __builtin_amdgcn_mfma_f32_16x16x32_bf16(a0, kf0, acc[jf], 0, 0, 0);
    acc[jf] = __builtin_amdgcn_mfma_f32_16x16x32_bf16(a1, kf1, acc[jf], 0, 0, 0);
  }

  for (int hh = 0; hh < HRATIO; ++hh) {
    const int n = g * HRATIO + hh;
    const short* vg = vT + ((size_t)b * NHEAD + n) * 64 * NPAD;
    s16x8 vf[7];
#pragma unroll
    for (int ks = 0; ks < 7; ++ks)
      vf[ks] = *(const s16x8*)(vg + (w * 16 + lm) * NPAD + ks * 32 + lh * 8);

    // ---- mask-mix + no-max softmax (shift-invariant; logits bounded) ----
#pragma unroll
    for (int r = 0; r < 4; ++r) {
      const int row = w * 16 + lh * 4 + r;
      const int i = it * 64 + row;
      const float* mr = mwp + (((size_t)n * 256 + i) * 16 + lm) * 16;
      f32x4 mv0 = *(const f32x4*)(mr);
      f32x4 mv1 = *(const f32x4*)(mr + 4);
      f32x4 mv2 = *(const f32x4*)(mr + 8);
      f32x4 mv3 = *(const f32x4*)(mr + 12);
      float sum = 0.f;
#pragma unroll
      for (int jf = 0; jf < 13; ++jf) {
        float mwv = (jf < 4) ? mv0[jf] : (jf < 8) ? mv1[jf - 4]
                  : (jf < 12) ? mv2[jf - 8] : mv3[jf - 12];
        float pe = __expf(acc[jf][r] * mwv);
        if (jf == 12 && lm >= 5) pe = 0.f;   // cols >= 197
        sum += pe;
        int byteoff = row * 512 + (((2 * jf + (lm >> 3)) ^ (row & 7)) << 4) + (lm & 7) * 2;
        *(short*)((char*)Pt + byteoff) = f2bf(pe);
      }
      {  // jf = 13: cols 208-223 invalid -> zeros
        int byteoff = row * 512 + (((26 + (lm >> 3)) ^ (row & 7)) << 4) + (lm & 7) * 2;
        *(short*)((char*)Pt + byteoff) = 0;
      }
#pragma unroll
      for (int off = 8; off; off >>= 1) sum += __shfl_xor(sum, off);
      if (lm == 0) rsb[row] = 1.f / sum;
    }
    __syncthreads();

    // ---- PV: wave w computes out dims w*16..+15 for all 64 rows ----
    __builtin_amdgcn_s_setprio(1);
    f32x4 oacc[4] = {};
#pragma unroll
    for (int fi = 0; fi < 4; ++fi)
#pragma unroll
      for (int ks = 0; ks < 7; ++ks) {
        s16x8 pa = *(const s16x8*)((const char*)Pt + (fi * 16 + lm) * 512 +
                                   (((ks * 4 + lh) ^ l7) << 4));
        oacc[fi] = __builtin_amdgcn_mfma_f32_16x16x32_bf16(pa, vf[ks], oacc[fi], 0, 0, 0);
      }
    __builtin_amdgcn_s_setprio(0);
#pragma unroll
    for (int fi = 0; fi < 4; ++fi)
#pragma unroll
      for (int r = 0; r < 4; ++r) {
        int ia = it * 64 + fi * 16 + lh * 4 + r;
        if (ia < NTOK) {
          float rsv = rsb[fi * 16 + lh * 4 + r];
          vec_b[((size_t)ia * BATCH + b) * DMODEL + n * 64 + w * 16 + lm] =
              f2bf(oacc[fi][r] * rsv);
        }
      }
    __syncthreads();
  }
}

// ---------- residual + LayerNorm: out = LN(h + proj_b) ----------
__global__ __launch_bounds__(256)
void ln_kernel(const float* __restrict__ h, const short* __restrict__ proj_b,
               float* __restrict__ out, const float* __restrict__ gamma,
               const float* __restrict__ beta) {
  const int m = blockIdx.x;
  const float* hrow = h + (size_t)m * DMODEL;
  const short* prow = proj_b + (size_t)m * DMODEL;
  float* orow = out + (size_t)m * DMODEL;
  const int tid = threadIdx.x;
  float v0 = hrow[tid] + bf2f(prow[tid]);
  float v1 = hrow[tid + 256] + bf2f(prow[tid + 256]);
  float v2 = hrow[tid + 512] + bf2f(prow[tid + 512]);
  float s = v0 + v1 + v2;
  float sq = v0 * v0 + v1 * v1 + v2 * v2;
#pragma unroll
  for (int off = 32; off; off >>= 1) {
    s += __shfl_xor(s, off);
    sq += __shfl_xor(sq, off);
  }
  __shared__ float ss[4], ssq[4];
  const int w = tid >> 6, lane = tid & 63;
  if (lane == 0) { ss[w] = s; ssq[w] = sq; }
  __syncthreads();
  s = ss[0] + ss[1] + ss[2] + ss[3];
  sq = ssq[0] + ssq[1] + ssq[2] + ssq[3];
  const float inv = 1.0f / (float)DMODEL;
  float mu = s * inv;
  float var = sq * inv - mu * mu;
  float rstd = rsqrtf(var + LNEPS);
  orow[tid] = gamma[tid] * (v0 - mu) * rstd + beta[tid];
  orow[tid + 256] = gamma[tid + 256] * (v1 - mu) * rstd + beta[tid + 256];
  orow[tid + 512] = gamma[tid + 512] * (v2 - mu) * rstd + beta[tid + 512];
}

extern "C" void kernel_launch(void* const* d_in, const int* in_sizes, int n_in,
                              void* d_out, int out_size, void* d_ws, size_t ws_size,
                              hipStream_t stream) {
  const float* h     = (const float*)d_in[0];
  const float* masks = (const float*)d_in[1];
  const float* Wq    = (const float*)d_in[2];
  const float* Wk    = (const float*)d_in[3];
  const float* Wv    = (const float*)d_in[4];
  const float* Wo    = (const float*)d_in[5];
  const float* mproj = (const float*)d_in[6];
  const float* gamma = (const float*)d_in[7];
  const float* beta  = (const float*)d_in[8];
  float* out = (float*)d_out;

  char* ws = (char*)d_ws;
  size_t o = 0;
  auto alloc = [&](size_t bytes) { size_t r = o; o += (bytes + 255) & ~(size_t)255; return r; };
  short* hb    = (short*)(ws + alloc((size_t)MPAD * DMODEL * 2));   // aliased: vec_b
  short* Cb    = (short*)(ws + alloc((size_t)MPAD * 1024 * 2));     // aliased: proj_b
  short* Wqkvb = (short*)(ws + alloc((size_t)1024 * DMODEL * 2));
  short* Wob   = (short*)(ws + alloc((size_t)DMODEL * DMODEL * 2));
  short* qp    = (short*)(ws + alloc((size_t)BATCH * GHEAD * NPAD * DHEAD * 2));
  short* kp    = (short*)(ws + alloc((size_t)BATCH * GHEAD * NPAD * DHEAD * 2));
  short* vT    = (short*)(ws + alloc((size_t)BATCH * NHEAD * DHEAD * NPAD * 2));
  float* mwp   = (float*)(ws + alloc((size_t)NHEAD * 256 * 16 * 16 * 4));
  short* vec_b = hb;   // hb dead after QKV gemm
  short* proj_b = Cb;  // Cb dead after packall

  prep_kernel<<<NB_H + NB_QKV + NB_WO, 256, 0, stream>>>(h, Wq, Wk, Wv, Wo, hb, Wqkvb, Wob);
  gemm_bt_kernel<<<dim3(1024 / 128, MPAD / 128), 256, 0, stream>>>(
      hb, Wqkvb, Cb, MROWS, DMODEL, 1024);
  packall_kernel<<<1216, 256, 0, stream>>>(Cb, masks, mproj, qp, kp, vT, mwp);
  attn_fused_kernel<<<dim3(4, BATCH, GHEAD), 256, 0, stream>>>(qp, kp, vT, mwp, vec_b);
  gemm_bt_kernel<<<dim3(DMODEL / 128, MPAD / 128), 256, 0, stream>>>(
      vec_b, Wob, proj_b, MROWS, DMODEL, DMODEL);
  ln_kernel<<<MROWS, 256, 0, stream>>>(h, proj_b, out, gamma, beta);
}